// Round 20
// baseline (8286.516 us; speedup 1.0000x reference)
//
#include <hip/hip_runtime.h>
#include <hip/hip_bf16.h>
#include <math.h>

// Round 20 (on R19, 6.91 ms): NOC=4 multi-ocT waves in both MFMA conv kernels.
// Each wave accumulates 4 oc-tiles over the same staged B LDS -> input fetch
// and staging /4 (R19 counters: FETCH 285 MB = 5.5x input, MfmaUtil 7.5%).
// Per-output MFMA sequence bit-identical -> z unchanged -> argmin unchanged.
// Everything else R19 verbatim. Diagnostic: absmax == 3.814697e-06.

static constexpr float kBNF = 0.9999950000374997f;

typedef short short8 __attribute__((ext_vector_type(8)));
typedef _Float16 half8 __attribute__((ext_vector_type(8)));
typedef float f32x4 __attribute__((ext_vector_type(4)));

// ---------------------------------------------------------------- conv0: 1->128, 3x3, s1, relu (B=1), fp32
__global__ __launch_bounds__(320) void conv0_k(const float* __restrict__ x,
                                               const float* __restrict__ w,
                                               const float* __restrict__ b,
                                               float* __restrict__ out) {
  const int H = 320, W = 320, OC = 128;
  int oy = blockIdx.x;
  int tx = threadIdx.x;
  __shared__ float in_s[3][W + 2];
  __shared__ float w_s[128 * 9];
  __shared__ float b_s[128];
  for (int e = tx; e < 3 * (W + 2); e += 320) {
    int r = e / (W + 2), c = e % (W + 2);
    int iy = oy + r - 1, ix = c - 1;
    float v = 0.f;
    if (iy >= 0 && iy < H && ix >= 0 && ix < W) v = x[iy * W + ix];
    in_s[r][c] = v;
  }
  for (int e = tx; e < 128 * 9; e += 320) w_s[e] = w[e];
  for (int e = tx; e < 128; e += 320) b_s[e] = b[e];
  __syncthreads();
  float iv[9];
#pragma unroll
  for (int r = 0; r < 3; ++r)
#pragma unroll
    for (int c = 0; c < 3; ++c) iv[r * 3 + c] = in_s[r][tx + c];
  for (int oc = 0; oc < OC; ++oc) {
    float acc = 0.f;
#pragma unroll
    for (int t = 0; t < 9; ++t) acc = fmaf(w_s[oc * 9 + t], iv[t], acc);
    float v32 = __fadd_rn(acc, b_s[oc]);
    v32 = __fmul_rn(v32, kBNF);
    out[(oc * H + oy) * W + tx] = fmaxf(v32, 0.f);
  }
}

// ---------------------------------------------------------------- conv3x3 weight prep -> fp16-split A-frags
__global__ __launch_bounds__(256) void prep_w3h_k(const float* __restrict__ w,
                                                  _Float16* __restrict__ wh,
                                                  int IC, int OC) {
  int i = blockIdx.x * 256 + threadIdx.x;
  int total = 2 * 9 * IC * OC;
  if (i >= total) return;
  int e = i & 7;
  int lane = (i >> 3) & 63;
  int rest = i >> 9;
  int ktiles = IC >> 5;
  int kT = rest % ktiles;
  int rest2 = rest / ktiles;
  int OCt = OC >> 4;
  int ocT = rest2 % OCt;
  int rest3 = rest2 / OCt;
  int tap = rest3 % 9;
  int split = rest3 / 9;
  int m = lane & 15, k = ((lane >> 4) << 3) + e;
  int oc = ocT * 16 + m, ic = kT * 32 + k;
  float v = w[((size_t)oc * IC + ic) * 9 + tap];
  _Float16 hi = (_Float16)v;
  wh[i] = (split == 0) ? hi : (_Float16)(v - (float)hi);
}

// ---------------------------------------------------------------- 3x3 conv S=1 via MFMA fp16-split, NOC ocT/wave
template <int NOC>
__global__ __launch_bounds__(256) void conv3s1_mfma_k(
    const float* __restrict__ in, const _Float16* __restrict__ wh,
    const float* __restrict__ bias, const float* __restrict__ skip,
    float* __restrict__ out, int IC, int HW_, int OC) {
  __shared__ __align__(16) _Float16 ldsH[3 * 20 * 40];
  __shared__ __align__(16) _Float16 ldsL[3 * 20 * 40];
  int t = threadIdx.x;
  int wv = t >> 6, l = t & 63;
  int px0 = blockIdx.x * 16;
  int oy = blockIdx.y;
  int ocT0 = (blockIdx.z * 4 + wv) * NOC;
  const int ktiles = IC >> 5;
  const int OCt = OC >> 4;
  int n = l & 15, koff = (l >> 4) * 8;
  f32x4 acc[NOC];
#pragma unroll
  for (int j = 0; j < NOC; ++j) acc[j] = {0.f, 0.f, 0.f, 0.f};
  const half8* wh8 = reinterpret_cast<const half8*>(wh);
  for (int kT = 0; kT < ktiles; ++kT) {
    __syncthreads();
    for (int e = t; e < 1728; e += 256) {
      int xi = e % 18;
      int rem = e / 18;
      int ic = rem & 31, r = rem >> 5;
      int iy = oy - 1 + r;
      int ix = px0 - 1 + xi;
      float v = 0.f;
      if (iy >= 0 && iy < HW_ && ix >= 0 && ix < HW_)
        v = in[((size_t)(kT * 32 + ic) * HW_ + iy) * HW_ + ix];
      _Float16 hi = (_Float16)v;
      ldsH[(r * 20 + xi) * 40 + ic] = hi;
      ldsL[(r * 20 + xi) * 40 + ic] = (_Float16)(v - (float)hi);
    }
    __syncthreads();
#pragma unroll
    for (int ky = 0; ky < 3; ++ky) {
#pragma unroll
      for (int kx = 0; kx < 3; ++kx) {
        int tap = ky * 3 + kx;
        half8 BH = *reinterpret_cast<const half8*>(&ldsH[(ky * 20 + n + kx) * 40 + koff]);
        half8 BL = *reinterpret_cast<const half8*>(&ldsL[(ky * 20 + n + kx) * 40 + koff]);
#pragma unroll
        for (int j = 0; j < NOC; ++j) {
          half8 AH = wh8[(((tap)*OCt + (ocT0 + j)) * ktiles + kT) * 64 + l];
          half8 AL = wh8[(((9 + tap) * OCt + (ocT0 + j)) * ktiles + kT) * 64 + l];
          acc[j] = __builtin_amdgcn_mfma_f32_16x16x32_f16(AH, BH, acc[j], 0, 0, 0);
          acc[j] = __builtin_amdgcn_mfma_f32_16x16x32_f16(AH, BL, acc[j], 0, 0, 0);
          acc[j] = __builtin_amdgcn_mfma_f32_16x16x32_f16(AL, BH, acc[j], 0, 0, 0);
        }
      }
    }
  }
  int ox = px0 + n;
#pragma unroll
  for (int j = 0; j < NOC; ++j) {
    int oc0 = (ocT0 + j) * 16 + ((l >> 4) << 2);
#pragma unroll
    for (int r = 0; r < 4; ++r) {
      int oc = oc0 + r;
      float bv = bias[oc];
      size_t idx = ((size_t)oc * HW_ + oy) * HW_ + ox;
      float v32 = __fadd_rn(acc[j][r], bv);
      v32 = __fmul_rn(v32, kBNF);
      v32 = __fadd_rn(v32, skip[idx]);
      out[idx] = fmaxf(v32, 0.f);
    }
  }
}

// ---------------------------------------------------------------- 3x3 conv S=2 via MFMA fp16-split, parity LDS, NOC
template <int NOC>
__global__ __launch_bounds__(256) void conv3s2_mfma_k(
    const float* __restrict__ in, const _Float16* __restrict__ wh,
    const float* __restrict__ bias, float* __restrict__ out,
    int IC, int IH, int IW, int OC, int OH, int OW) {
  __shared__ __align__(16) _Float16 ldsEH[3 * 17 * 40];
  __shared__ __align__(16) _Float16 ldsEL[3 * 17 * 40];
  __shared__ __align__(16) _Float16 ldsOH[3 * 16 * 40];
  __shared__ __align__(16) _Float16 ldsOL[3 * 16 * 40];
  int t = threadIdx.x;
  int wv = t >> 6, l = t & 63;
  int px0 = blockIdx.x * 16;
  int oy = blockIdx.y;
  int ocT0 = (blockIdx.z * 4 + wv) * NOC;
  const int ktiles = IC >> 5;
  const int OCt = OC >> 4;
  int n = l & 15, koff = (l >> 4) * 8;
  f32x4 acc[NOC];
#pragma unroll
  for (int j = 0; j < NOC; ++j) acc[j] = {0.f, 0.f, 0.f, 0.f};
  const half8* wh8 = reinterpret_cast<const half8*>(wh);
  for (int kT = 0; kT < ktiles; ++kT) {
    __syncthreads();
    for (int e = t; e < 3168; e += 256) {
      int ic = e & 31;
      int rem = e >> 5;
      int xi = rem % 33, ky = rem / 33;
      int iy = oy * 2 - 1 + ky;
      int ix = px0 * 2 - 1 + xi;
      float v = 0.f;
      if (iy >= 0 && iy < IH && ix >= 0 && ix < IW)
        v = in[((size_t)(kT * 32 + ic) * IH + iy) * IW + ix];
      _Float16 hi = (_Float16)v;
      _Float16 lo = (_Float16)(v - (float)hi);
      int hrow = xi >> 1;
      if (xi & 1) {
        ldsOH[(ky * 16 + hrow) * 40 + ic] = hi;
        ldsOL[(ky * 16 + hrow) * 40 + ic] = lo;
      } else {
        ldsEH[(ky * 17 + hrow) * 40 + ic] = hi;
        ldsEL[(ky * 17 + hrow) * 40 + ic] = lo;
      }
    }
    __syncthreads();
#pragma unroll
    for (int ky = 0; ky < 3; ++ky) {
#pragma unroll
      for (int kx = 0; kx < 3; ++kx) {
        int tap = ky * 3 + kx;
        half8 BH, BL;
        if (kx == 0) {
          BH = *reinterpret_cast<const half8*>(&ldsEH[(ky * 17 + n) * 40 + koff]);
          BL = *reinterpret_cast<const half8*>(&ldsEL[(ky * 17 + n) * 40 + koff]);
        } else if (kx == 1) {
          BH = *reinterpret_cast<const half8*>(&ldsOH[(ky * 16 + n) * 40 + koff]);
          BL = *reinterpret_cast<const half8*>(&ldsOL[(ky * 16 + n) * 40 + koff]);
        } else {
          BH = *reinterpret_cast<const half8*>(&ldsEH[(ky * 17 + n + 1) * 40 + koff]);
          BL = *reinterpret_cast<const half8*>(&ldsEL[(ky * 17 + n + 1) * 40 + koff]);
        }
#pragma unroll
        for (int j = 0; j < NOC; ++j) {
          half8 AH = wh8[(((tap)*OCt + (ocT0 + j)) * ktiles + kT) * 64 + l];
          half8 AL = wh8[(((9 + tap) * OCt + (ocT0 + j)) * ktiles + kT) * 64 + l];
          acc[j] = __builtin_amdgcn_mfma_f32_16x16x32_f16(AH, BH, acc[j], 0, 0, 0);
          acc[j] = __builtin_amdgcn_mfma_f32_16x16x32_f16(AH, BL, acc[j], 0, 0, 0);
          acc[j] = __builtin_amdgcn_mfma_f32_16x16x32_f16(AL, BH, acc[j], 0, 0, 0);
        }
      }
    }
  }
  int ox = px0 + n;
#pragma unroll
  for (int j = 0; j < NOC; ++j) {
    int oc0 = (ocT0 + j) * 16 + ((l >> 4) << 2);
#pragma unroll
    for (int r = 0; r < 4; ++r) {
      int oc = oc0 + r;
      float bv = bias[oc];
      size_t idx = ((size_t)oc * OH + oy) * OW + ox;
      float v32 = __fadd_rn(acc[j][r], bv);
      v32 = __fmul_rn(v32, kBNF);
      out[idx] = fmaxf(v32, 0.f);
    }
  }
}

// ---------------------------------------------------------------- 1x1 conv, fp32 acc (R15)
template <int S, bool RELU>
__global__ __launch_bounds__(256) void conv1x1_k(
    const float* __restrict__ in, const float* __restrict__ w,
    const float* __restrict__ bias, float* __restrict__ out,
    int IC, int IH, int IW, int OC, int OH, int OW) {
  __shared__ float in_s[16][64];
  __shared__ float w_s[16][64];
  const int P = OH * OW;
  int t = threadIdx.x;
  int p0 = blockIdx.x * 64;
  int oc0 = blockIdx.y * 64;
  int oc4 = (t >> 4) * 4, px4 = (t & 15) * 4;
  float acc[4][4] = {};
  for (int ic0 = 0; ic0 < IC; ic0 += 16) {
    __syncthreads();
    {
      int e = t;
#pragma unroll
      for (int k = 0; k < 4; ++k, e += 256) {
        int icr = e >> 6, pxr = e & 63;
        int p = p0 + pxr;
        float v = 0.f;
        if (p < P) {
          int oy = p / OW, ox = p % OW;
          v = in[((ic0 + icr) * IH + oy * S) * IW + ox * S];
        }
        in_s[icr][pxr] = v;
      }
      e = t;
#pragma unroll
      for (int k = 0; k < 4; ++k, e += 256) {
        int icr = e >> 6, ocr = e & 63;
        w_s[icr][ocr] = w[(oc0 + ocr) * IC + ic0 + icr];
      }
    }
    __syncthreads();
#pragma unroll
    for (int icr = 0; icr < 16; ++icr) {
      float4 iv = *reinterpret_cast<const float4*>(&in_s[icr][px4]);
      float4 wv = *reinterpret_cast<const float4*>(&w_s[icr][oc4]);
      const float* ip = (const float*)&iv;
      const float* wp = (const float*)&wv;
#pragma unroll
      for (int o = 0; o < 4; ++o)
#pragma unroll
        for (int p = 0; p < 4; ++p)
          acc[o][p] = fmaf(wp[o], ip[p], acc[o][p]);
    }
  }
  int p = p0 + px4;
  if (p < P) {
    int oy = p / OW, ox = p % OW;
#pragma unroll
    for (int o = 0; o < 4; ++o) {
      int oc = oc0 + oc4 + o;
      float bv = bias[oc];
      float4 rv;
      float* rp = (float*)&rv;
#pragma unroll
      for (int pp = 0; pp < 4; ++pp) {
        float v32 = __fadd_rn(acc[o][pp], bv);
        v32 = __fmul_rn(v32, kBNF);
        if (RELU) v32 = fmaxf(v32, 0.f);
        rp[pp] = v32;
      }
      *reinterpret_cast<float4*>(&out[((size_t)oc * OH + oy) * OW + ox]) = rv;
    }
  }
}

// ---------------------------------------------------------------- ConvT weight prep -> bf16 A-fragments (R14)
__global__ __launch_bounds__(256) void prep_wb_k(const float* __restrict__ w,
                                                 __hip_bfloat16* __restrict__ wb,
                                                 int IC, int OC) {
  int i = blockIdx.x * 256 + threadIdx.x;
  int total = 16 * IC * OC;
  if (i >= total) return;
  int per_cfg = IC * OC;
  int cfg = i / per_cfg;
  int r = i - cfg * per_cfg;
  int ktiles = IC >> 5;
  int ocT = r / (ktiles * 512);
  int r2 = r - ocT * (ktiles * 512);
  int kT = r2 >> 9;
  int f = r2 & 511;
  int lane = f >> 3, e = f & 7;
  int m = lane & 15, kk = ((lane >> 4) << 3) + e;
  int oc = ocT * 16 + m, ic = kT * 32 + kk;
  int kyb = cfg >> 3, ty = (cfg >> 2) & 1, kx = cfg & 3;
  int ky = kyb + 2 * ty;
  wb[i] = __float2bfloat16(w[((size_t)ic * OC + oc) * 16 + ky * 4 + kx]);
}

// ---------------------------------------------------------------- ConvT k4 s2 p1 via MFMA bf16 (R14, validated)
__global__ __launch_bounds__(256) void convt_mfma_k(
    const float* __restrict__ in, const __hip_bfloat16* __restrict__ wb,
    const float* __restrict__ bias, float* __restrict__ out,
    int IC, int IH, int IW, int OC, int OH, int OW) {
  __shared__ __align__(16) __hip_bfloat16 lds[2 * 18 * 40];
  int t = threadIdx.x;
  int wv = t >> 6, l = t & 63;
  int ox0 = blockIdx.x * 32;
  int oy = blockIdx.y;
  int oc0w = blockIdx.z * 64 + wv * 16;
  int kyb = (oy & 1) ? 0 : 1;
  int hb = ox0 >> 1;
  int iy0n = oy + 1 - kyb;
  int iy0 = iy0n >> 1;
  bool ok0 = (iy0 < IH);
  int iy1n = oy + 1 - kyb - 2;
  int iy1 = iy1n >> 1;
  bool ok1 = (iy1n >= 0) && (iy1 < IH);
  f32x4 accE = {0.f, 0.f, 0.f, 0.f};
  f32x4 accO = {0.f, 0.f, 0.f, 0.f};
  const int ktiles = IC >> 5;
  int n = l & 15, koff = (l >> 4) * 8;
  const short8* wb8 = reinterpret_cast<const short8*>(wb);
  int ocT = oc0w >> 4;
  const int OCt = OC >> 4;
  for (int kT = 0; kT < ktiles; ++kT) {
    __syncthreads();
    for (int e = t; e < 1152; e += 256) {
      int ic = e / 36;
      int r = e - ic * 36;
      int ty = r / 18, xi = r - ty * 18;
      int ix = hb - 1 + xi;
      int iy = ty ? iy1 : iy0;
      bool ok = ty ? ok1 : ok0;
      float v = 0.f;
      if (ok && ix >= 0 && ix < IW)
        v = in[((size_t)(kT * 32 + ic) * IH + iy) * IW + ix];
      lds[(ty * 18 + xi) * 40 + ic] = __float2bfloat16(v);
    }
    __syncthreads();
#pragma unroll
    for (int ty = 0; ty < 2; ++ty) {
      short8 A0 = wb8[((((kyb * 2 + ty) * 4 + 0) * OCt + ocT) * ktiles + kT) * 64 + l];
      short8 A1 = wb8[((((kyb * 2 + ty) * 4 + 1) * OCt + ocT) * ktiles + kT) * 64 + l];
      short8 A2 = wb8[((((kyb * 2 + ty) * 4 + 2) * OCt + ocT) * ktiles + kT) * 64 + l];
      short8 A3 = wb8[((((kyb * 2 + ty) * 4 + 3) * OCt + ocT) * ktiles + kT) * 64 + l];
      short8 b0 = *reinterpret_cast<const short8*>(&lds[(ty * 18 + 0 + n) * 40 + koff]);
      short8 b1 = *reinterpret_cast<const short8*>(&lds[(ty * 18 + 1 + n) * 40 + koff]);
      short8 b2 = *reinterpret_cast<const short8*>(&lds[(ty * 18 + 2 + n) * 40 + koff]);
      accE = __builtin_amdgcn_mfma_f32_16x16x32_bf16(A1, b1, accE, 0, 0, 0);
      accE = __builtin_amdgcn_mfma_f32_16x16x32_bf16(A3, b0, accE, 0, 0, 0);
      accO = __builtin_amdgcn_mfma_f32_16x16x32_bf16(A0, b2, accO, 0, 0, 0);
      accO = __builtin_amdgcn_mfma_f32_16x16x32_bf16(A2, b1, accO, 0, 0, 0);
    }
  }
  int ocr0 = oc0w + ((l >> 4) << 2);
  int oxE = ox0 + 2 * n;
  int oxO = ox0 + 1 + 2 * n;
#pragma unroll
  for (int r = 0; r < 4; ++r) {
    float bv = bias[ocr0 + r];
    size_t rowbase = ((size_t)(ocr0 + r) * OH + oy) * OW;
    out[rowbase + oxE] = fmaxf((accE[r] + bv) * kBNF, 0.f);
    out[rowbase + oxO] = fmaxf((accO[r] + bv) * kBNF, 0.f);
  }
}

// ---------------------------------------------------------------- final 3x3 conv 128->1 + sigmoid (R9)
__global__ __launch_bounds__(320) void dow_k(const float* __restrict__ in,
                                             const float* __restrict__ w,
                                             const float* __restrict__ bias,
                                             float* __restrict__ out) {
  const int H = 320, W = 320, IC = 128;
  int oy = blockIdx.x;
  int tx = threadIdx.x;
  __shared__ float in_s[4][3][W + 2];
  __shared__ float w_s[IC * 9];
  for (int e = tx; e < IC * 9; e += 320) w_s[e] = w[e];
  float acc = 0.f;
  for (int ic0 = 0; ic0 < IC; ic0 += 4) {
    __syncthreads();
    for (int e = tx; e < 4 * 3 * (W + 2); e += 320) {
      int icr = e / (3 * (W + 2));
      int rem = e - icr * (3 * (W + 2));
      int r = rem / (W + 2), c = rem - r * (W + 2);
      int iy = oy + r - 1, ix = c - 1;
      float v = 0.f;
      if (iy >= 0 && iy < H && ix >= 0 && ix < W)
        v = in[((ic0 + icr) * H + iy) * W + ix];
      in_s[icr][r][c] = v;
    }
    __syncthreads();
#pragma unroll
    for (int icr = 0; icr < 4; ++icr)
#pragma unroll
      for (int r = 0; r < 3; ++r)
#pragma unroll
        for (int c = 0; c < 3; ++c)
          acc = fmaf(w_s[(ic0 + icr) * 9 + r * 3 + c], in_s[icr][r][tx + c], acc);
  }
  acc += bias[0];
  out[oy * W + tx] = 1.f / (1.f + expf(-acc));
}

// ---------------------------------------------------------------- codebook sq-norms: numpy-pairwise fp32
__global__ __launch_bounds__(256) void cbprep_np(const float* __restrict__ cb,
                                                 float* __restrict__ c2f) {
  int e = blockIdx.x, t = threadIdx.x;
  __shared__ float a[256];
  a[t] = cb[e * 256 + t];
  __syncthreads();
  if (t == 0) {
    float tot = 0.f;
    for (int h = 0; h < 2; ++h) {
      const float* p = a + h * 128;
      float r[8];
#pragma unroll
      for (int j = 0; j < 8; ++j) r[j] = __fmul_rn(p[j], p[j]);
      for (int i = 8; i < 128; i += 8)
#pragma unroll
        for (int j = 0; j < 8; ++j) r[j] = __fadd_rn(r[j], __fmul_rn(p[i + j], p[i + j]));
      float s = __fadd_rn(__fadd_rn(__fadd_rn(r[0], r[1]), __fadd_rn(r[2], r[3])),
                          __fadd_rn(__fadd_rn(r[4], r[5]), __fadd_rn(r[6], r[7])));
      tot = (h == 0) ? s : __fadd_rn(tot, s);
    }
    c2f[e] = tot;
  }
}

// ---------------------------------------------------------------- VQ: 4 rows/block (R15, validated)
__global__ __launch_bounds__(256) void vq_ref_k(const float* __restrict__ z,
                                                const float* __restrict__ cb,
                                                const float* __restrict__ c2f,
                                                float* __restrict__ zq_out,
                                                float* __restrict__ idx_out) {
  int n0 = blockIdx.x * 4;
  int t = threadIdx.x;
  __shared__ float f[4][256];
  __shared__ float dist[4][1024];
  __shared__ float rr[4][2][8];
  __shared__ float f2s[4];
  __shared__ int bestIdx[4];
  for (int e = t; e < 1024; e += 256) {
    int r = e >> 8, c = e & 255;
    f[r][c] = z[(size_t)(n0 + r) * 256 + c];
  }
  __syncthreads();
  if (t < 64) {
    int row = t >> 4, hh = (t >> 3) & 1, j = t & 7;
    const float* p = f[row] + hh * 128;
    float r = __fmul_rn(p[j], p[j]);
    for (int i = 8; i < 128; i += 8) r = __fadd_rn(r, __fmul_rn(p[i + j], p[i + j]));
    rr[row][hh][j] = r;
  }
  __syncthreads();
  if (t < 4) {
    float s0 = __fadd_rn(__fadd_rn(__fadd_rn(rr[t][0][0], rr[t][0][1]), __fadd_rn(rr[t][0][2], rr[t][0][3])),
                         __fadd_rn(__fadd_rn(rr[t][0][4], rr[t][0][5]), __fadd_rn(rr[t][0][6], rr[t][0][7])));
    float s1 = __fadd_rn(__fadd_rn(__fadd_rn(rr[t][1][0], rr[t][1][1]), __fadd_rn(rr[t][1][2], rr[t][1][3])),
                         __fadd_rn(__fadd_rn(rr[t][1][4], rr[t][1][5]), __fadd_rn(rr[t][1][6], rr[t][1][7])));
    f2s[t] = __fadd_rn(s0, s1);
  }
  __syncthreads();
  for (int e = t; e < 1024; e += 256) {
    const float4* cbe = reinterpret_cast<const float4*>(cb + (size_t)e * 256);
    double d0 = 0.0, d1 = 0.0, d2 = 0.0, d3 = 0.0;
    for (int d = 0; d < 64; ++d) {
      float4 c4 = cbe[d];
      float4 f0 = *reinterpret_cast<const float4*>(&f[0][d * 4]);
      float4 f1 = *reinterpret_cast<const float4*>(&f[1][d * 4]);
      float4 f2v = *reinterpret_cast<const float4*>(&f[2][d * 4]);
      float4 f3 = *reinterpret_cast<const float4*>(&f[3][d * 4]);
      d0 = fma((double)f0.x, (double)c4.x, d0); d0 = fma((double)f0.y, (double)c4.y, d0);
      d0 = fma((double)f0.z, (double)c4.z, d0); d0 = fma((double)f0.w, (double)c4.w, d0);
      d1 = fma((double)f1.x, (double)c4.x, d1); d1 = fma((double)f1.y, (double)c4.y, d1);
      d1 = fma((double)f1.z, (double)c4.z, d1); d1 = fma((double)f1.w, (double)c4.w, d1);
      d2 = fma((double)f2v.x, (double)c4.x, d2); d2 = fma((double)f2v.y, (double)c4.y, d2);
      d2 = fma((double)f2v.z, (double)c4.z, d2); d2 = fma((double)f2v.w, (double)c4.w, d2);
      d3 = fma((double)f3.x, (double)c4.x, d3); d3 = fma((double)f3.y, (double)c4.y, d3);
      d3 = fma((double)f3.z, (double)c4.z, d3); d3 = fma((double)f3.w, (double)c4.w, d3);
    }
    float c2e = c2f[e];
    dist[0][e] = __fsub_rn(__fadd_rn(f2s[0], c2e), __fmul_rn(2.f, (float)d0));
    dist[1][e] = __fsub_rn(__fadd_rn(f2s[1], c2e), __fmul_rn(2.f, (float)d1));
    dist[2][e] = __fsub_rn(__fadd_rn(f2s[2], c2e), __fmul_rn(2.f, (float)d2));
    dist[3][e] = __fsub_rn(__fadd_rn(f2s[3], c2e), __fmul_rn(2.f, (float)d3));
  }
  __syncthreads();
  {
    int row = t >> 6, l = t & 63;
    float bv = dist[row][l];
    int bi = l;
    for (int e = l + 64; e < 1024; e += 64) {
      float v = dist[row][e];
      if (v < bv) { bv = v; bi = e; }
    }
#pragma unroll
    for (int m = 1; m < 64; m <<= 1) {
      float ov = __shfl_xor(bv, m, 64);
      int oi = __shfl_xor(bi, m, 64);
      if (ov < bv || (ov == bv && oi < bi)) { bv = ov; bi = oi; }
    }
    if (l == 0) {
      bestIdx[row] = bi;
      idx_out[n0 + row] = (float)bi;
    }
  }
  __syncthreads();
#pragma unroll
  for (int r = 0; r < 4; ++r)
    zq_out[(size_t)(n0 + r) * 256 + t] = cb[(size_t)bestIdx[r] * 256 + t];
}

// ================================================================ host
extern "C" void kernel_launch(void* const* d_in, const int* in_sizes, int n_in,
                              void* d_out, int out_size, void* d_ws, size_t ws_size,
                              hipStream_t stream) {
  const float* x = (const float*)d_in[0];
  const float* w0 = (const float*)d_in[1];
  const float* b0 = (const float*)d_in[2];
  const float* a_c1w = (const float*)d_in[3];
  const float* a_c1b = (const float*)d_in[4];
  const float* a_c2w = (const float*)d_in[5];
  const float* a_c2b = (const float*)d_in[6];
  const float* a_scw = (const float*)d_in[7];
  const float* a_scb = (const float*)d_in[8];
  const float* b_c1w = (const float*)d_in[9];
  const float* b_c1b = (const float*)d_in[10];
  const float* b_c2w = (const float*)d_in[11];
  const float* b_c2b = (const float*)d_in[12];
  const float* b_scw = (const float*)d_in[13];
  const float* b_scb = (const float*)d_in[14];
  const float* ew = (const float*)d_in[15];
  const float* eb = (const float*)d_in[16];
  const float* cb = (const float*)d_in[17];
  const float* d0w = (const float*)d_in[18];
  const float* d0b = (const float*)d_in[19];
  const float* dt1w = (const float*)d_in[20];
  const float* dt1b = (const float*)d_in[21];
  const float* dt2w = (const float*)d_in[22];
  const float* dt2b = (const float*)d_in[23];
  const float* doww = (const float*)d_in[24];
  const float* dob = (const float*)d_in[25];

  // ws (floats): A 13.1M | B 6.55M | C 6.55M | c2f 1024  ~= 105 MB (unchanged)
  float* ws = (float*)d_ws;
  float* A = ws;
  float* Bf = ws + 13107200;
  float* Cf = ws + 19660800;
  float* c2f = ws + 26214400;
  _Float16* wh_ac1 = (_Float16*)(void*)Cf;
  _Float16* wh_bc1 = (_Float16*)(void*)(Bf + 3300000);
  _Float16* wh_ac2 = (_Float16*)(void*)(A + 6600000);
  _Float16* wh_bc2 = (_Float16*)(void*)(A + 3300000);
  __hip_bfloat16* wb_dt1 = (__hip_bfloat16*)(void*)A;
  __hip_bfloat16* wb_dt2 = (__hip_bfloat16*)(void*)(Bf + 3400000);

  float* outf = (float*)d_out;
  float* recon = outf;
  float* zq = outf + 409600;
  float* idxo = zq + 6553600;

  cbprep_np<<<1024, 256, 0, stream>>>(cb, c2f);

  for (int b = 0; b < 4; ++b) {
    const float* xb = x + (size_t)b * 102400;
    float* zqb = zq + (size_t)b * 1638400;
    float* idxb = idxo + (size_t)b * 6400;
    float* reconb = recon + (size_t)b * 102400;

    // encoder (all 3x3 layers via fp16-split MFMA, NOC=4)
    conv0_k<<<320, 320, 0, stream>>>(xb, w0, b0, A);
    prep_w3h_k<<<2304, 256, 0, stream>>>(a_c1w, wh_ac1, 128, 256);
    conv3s2_mfma_k<4><<<dim3(10, 160, 1), 256, 0, stream>>>(
        A, wh_ac1, a_c1b, Bf, 128, 320, 320, 256, 160, 160);
    conv1x1_k<2, false><<<dim3(400, 4), 256, 0, stream>>>(
        A, a_scw, a_scb, Cf, 128, 320, 320, 256, 160, 160);
    prep_w3h_k<<<4608, 256, 0, stream>>>(a_c2w, wh_ac2, 256, 256);
    conv3s1_mfma_k<4><<<dim3(10, 160, 1), 256, 0, stream>>>(
        Bf, wh_ac2, a_c2b, Cf, A, 256, 160, 256);
    prep_w3h_k<<<9216, 256, 0, stream>>>(b_c1w, wh_bc1, 256, 512);
    conv3s2_mfma_k<4><<<dim3(5, 80, 2), 256, 0, stream>>>(
        A, wh_bc1, b_c1b, Bf, 256, 160, 160, 512, 80, 80);
    conv1x1_k<2, false><<<dim3(100, 8), 256, 0, stream>>>(
        A, b_scw, b_scb, Cf, 256, 160, 160, 512, 80, 80);
    prep_w3h_k<<<18432, 256, 0, stream>>>(b_c2w, wh_bc2, 512, 512);
    conv3s1_mfma_k<4><<<dim3(5, 80, 2), 256, 0, stream>>>(
        Bf, wh_bc2, b_c2b, Cf, A, 512, 80, 512);
    conv1x1_k<1, false><<<dim3(100, 4), 256, 0, stream>>>(
        A, ew, eb, Cf, 512, 80, 80, 256, 80, 80);
    // VQ
    vq_ref_k<<<1600, 256, 0, stream>>>(Cf, cb, c2f, zqb, idxb);
    // decoder: bf16 MFMA ConvT (R14)
    prep_wb_k<<<8192, 256, 0, stream>>>(dt1w, wb_dt1, 512, 256);
    prep_wb_k<<<2048, 256, 0, stream>>>(dt2w, wb_dt2, 256, 128);
    conv1x1_k<1, true><<<dim3(100, 8), 256, 0, stream>>>(
        zqb, d0w, d0b, Bf, 256, 80, 80, 512, 80, 80);
    convt_mfma_k<<<dim3(5, 160, 4), 256, 0, stream>>>(
        Bf, wb_dt1, dt1b, Cf, 512, 80, 80, 256, 160, 160);
    convt_mfma_k<<<dim3(10, 320, 2), 256, 0, stream>>>(
        Cf, wb_dt2, dt2b, A, 256, 160, 160, 128, 320, 320);
    dow_k<<<320, 320, 0, stream>>>(A, doww, dob, reconb);
  }
}

// Round 21
// 6530.449 us; speedup vs baseline: 1.2689x; 1.2689x over previous
//
#include <hip/hip_runtime.h>
#include <hip/hip_bf16.h>
#include <math.h>

// Round 21: NOC=2 (interpolating measured endpoints NOC=1: 6.91 ms fetch-bound,
// NOC=4: 8.29 ms latency-bound). Grid z doubled vs R20. Per-output MFMA
// sequence bit-identical -> z unchanged. Diagnostic: absmax == 3.814697e-06.

static constexpr float kBNF = 0.9999950000374997f;

typedef short short8 __attribute__((ext_vector_type(8)));
typedef _Float16 half8 __attribute__((ext_vector_type(8)));
typedef float f32x4 __attribute__((ext_vector_type(4)));

// ---------------------------------------------------------------- conv0: 1->128, 3x3, s1, relu (B=1), fp32
__global__ __launch_bounds__(320) void conv0_k(const float* __restrict__ x,
                                               const float* __restrict__ w,
                                               const float* __restrict__ b,
                                               float* __restrict__ out) {
  const int H = 320, W = 320, OC = 128;
  int oy = blockIdx.x;
  int tx = threadIdx.x;
  __shared__ float in_s[3][W + 2];
  __shared__ float w_s[128 * 9];
  __shared__ float b_s[128];
  for (int e = tx; e < 3 * (W + 2); e += 320) {
    int r = e / (W + 2), c = e % (W + 2);
    int iy = oy + r - 1, ix = c - 1;
    float v = 0.f;
    if (iy >= 0 && iy < H && ix >= 0 && ix < W) v = x[iy * W + ix];
    in_s[r][c] = v;
  }
  for (int e = tx; e < 128 * 9; e += 320) w_s[e] = w[e];
  for (int e = tx; e < 128; e += 320) b_s[e] = b[e];
  __syncthreads();
  float iv[9];
#pragma unroll
  for (int r = 0; r < 3; ++r)
#pragma unroll
    for (int c = 0; c < 3; ++c) iv[r * 3 + c] = in_s[r][tx + c];
  for (int oc = 0; oc < OC; ++oc) {
    float acc = 0.f;
#pragma unroll
    for (int t = 0; t < 9; ++t) acc = fmaf(w_s[oc * 9 + t], iv[t], acc);
    float v32 = __fadd_rn(acc, b_s[oc]);
    v32 = __fmul_rn(v32, kBNF);
    out[(oc * H + oy) * W + tx] = fmaxf(v32, 0.f);
  }
}

// ---------------------------------------------------------------- conv3x3 weight prep -> fp16-split A-frags
__global__ __launch_bounds__(256) void prep_w3h_k(const float* __restrict__ w,
                                                  _Float16* __restrict__ wh,
                                                  int IC, int OC) {
  int i = blockIdx.x * 256 + threadIdx.x;
  int total = 2 * 9 * IC * OC;
  if (i >= total) return;
  int e = i & 7;
  int lane = (i >> 3) & 63;
  int rest = i >> 9;
  int ktiles = IC >> 5;
  int kT = rest % ktiles;
  int rest2 = rest / ktiles;
  int OCt = OC >> 4;
  int ocT = rest2 % OCt;
  int rest3 = rest2 / OCt;
  int tap = rest3 % 9;
  int split = rest3 / 9;
  int m = lane & 15, k = ((lane >> 4) << 3) + e;
  int oc = ocT * 16 + m, ic = kT * 32 + k;
  float v = w[((size_t)oc * IC + ic) * 9 + tap];
  _Float16 hi = (_Float16)v;
  wh[i] = (split == 0) ? hi : (_Float16)(v - (float)hi);
}

// ---------------------------------------------------------------- 3x3 conv S=1 via MFMA fp16-split, NOC ocT/wave
template <int NOC>
__global__ __launch_bounds__(256) void conv3s1_mfma_k(
    const float* __restrict__ in, const _Float16* __restrict__ wh,
    const float* __restrict__ bias, const float* __restrict__ skip,
    float* __restrict__ out, int IC, int HW_, int OC) {
  __shared__ __align__(16) _Float16 ldsH[3 * 20 * 40];
  __shared__ __align__(16) _Float16 ldsL[3 * 20 * 40];
  int t = threadIdx.x;
  int wv = t >> 6, l = t & 63;
  int px0 = blockIdx.x * 16;
  int oy = blockIdx.y;
  int ocT0 = (blockIdx.z * 4 + wv) * NOC;
  const int ktiles = IC >> 5;
  const int OCt = OC >> 4;
  int n = l & 15, koff = (l >> 4) * 8;
  f32x4 acc[NOC];
#pragma unroll
  for (int j = 0; j < NOC; ++j) acc[j] = {0.f, 0.f, 0.f, 0.f};
  const half8* wh8 = reinterpret_cast<const half8*>(wh);
  for (int kT = 0; kT < ktiles; ++kT) {
    __syncthreads();
    for (int e = t; e < 1728; e += 256) {
      int xi = e % 18;
      int rem = e / 18;
      int ic = rem & 31, r = rem >> 5;
      int iy = oy - 1 + r;
      int ix = px0 - 1 + xi;
      float v = 0.f;
      if (iy >= 0 && iy < HW_ && ix >= 0 && ix < HW_)
        v = in[((size_t)(kT * 32 + ic) * HW_ + iy) * HW_ + ix];
      _Float16 hi = (_Float16)v;
      ldsH[(r * 20 + xi) * 40 + ic] = hi;
      ldsL[(r * 20 + xi) * 40 + ic] = (_Float16)(v - (float)hi);
    }
    __syncthreads();
#pragma unroll
    for (int ky = 0; ky < 3; ++ky) {
#pragma unroll
      for (int kx = 0; kx < 3; ++kx) {
        int tap = ky * 3 + kx;
        half8 BH = *reinterpret_cast<const half8*>(&ldsH[(ky * 20 + n + kx) * 40 + koff]);
        half8 BL = *reinterpret_cast<const half8*>(&ldsL[(ky * 20 + n + kx) * 40 + koff]);
#pragma unroll
        for (int j = 0; j < NOC; ++j) {
          half8 AH = wh8[(((tap)*OCt + (ocT0 + j)) * ktiles + kT) * 64 + l];
          half8 AL = wh8[(((9 + tap) * OCt + (ocT0 + j)) * ktiles + kT) * 64 + l];
          acc[j] = __builtin_amdgcn_mfma_f32_16x16x32_f16(AH, BH, acc[j], 0, 0, 0);
          acc[j] = __builtin_amdgcn_mfma_f32_16x16x32_f16(AH, BL, acc[j], 0, 0, 0);
          acc[j] = __builtin_amdgcn_mfma_f32_16x16x32_f16(AL, BH, acc[j], 0, 0, 0);
        }
      }
    }
  }
  int ox = px0 + n;
#pragma unroll
  for (int j = 0; j < NOC; ++j) {
    int oc0 = (ocT0 + j) * 16 + ((l >> 4) << 2);
#pragma unroll
    for (int r = 0; r < 4; ++r) {
      int oc = oc0 + r;
      float bv = bias[oc];
      size_t idx = ((size_t)oc * HW_ + oy) * HW_ + ox;
      float v32 = __fadd_rn(acc[j][r], bv);
      v32 = __fmul_rn(v32, kBNF);
      v32 = __fadd_rn(v32, skip[idx]);
      out[idx] = fmaxf(v32, 0.f);
    }
  }
}

// ---------------------------------------------------------------- 3x3 conv S=2 via MFMA fp16-split, parity LDS, NOC
template <int NOC>
__global__ __launch_bounds__(256) void conv3s2_mfma_k(
    const float* __restrict__ in, const _Float16* __restrict__ wh,
    const float* __restrict__ bias, float* __restrict__ out,
    int IC, int IH, int IW, int OC, int OH, int OW) {
  __shared__ __align__(16) _Float16 ldsEH[3 * 17 * 40];
  __shared__ __align__(16) _Float16 ldsEL[3 * 17 * 40];
  __shared__ __align__(16) _Float16 ldsOH[3 * 16 * 40];
  __shared__ __align__(16) _Float16 ldsOL[3 * 16 * 40];
  int t = threadIdx.x;
  int wv = t >> 6, l = t & 63;
  int px0 = blockIdx.x * 16;
  int oy = blockIdx.y;
  int ocT0 = (blockIdx.z * 4 + wv) * NOC;
  const int ktiles = IC >> 5;
  const int OCt = OC >> 4;
  int n = l & 15, koff = (l >> 4) * 8;
  f32x4 acc[NOC];
#pragma unroll
  for (int j = 0; j < NOC; ++j) acc[j] = {0.f, 0.f, 0.f, 0.f};
  const half8* wh8 = reinterpret_cast<const half8*>(wh);
  for (int kT = 0; kT < ktiles; ++kT) {
    __syncthreads();
    for (int e = t; e < 3168; e += 256) {
      int ic = e & 31;
      int rem = e >> 5;
      int xi = rem % 33, ky = rem / 33;
      int iy = oy * 2 - 1 + ky;
      int ix = px0 * 2 - 1 + xi;
      float v = 0.f;
      if (iy >= 0 && iy < IH && ix >= 0 && ix < IW)
        v = in[((size_t)(kT * 32 + ic) * IH + iy) * IW + ix];
      _Float16 hi = (_Float16)v;
      _Float16 lo = (_Float16)(v - (float)hi);
      int hrow = xi >> 1;
      if (xi & 1) {
        ldsOH[(ky * 16 + hrow) * 40 + ic] = hi;
        ldsOL[(ky * 16 + hrow) * 40 + ic] = lo;
      } else {
        ldsEH[(ky * 17 + hrow) * 40 + ic] = hi;
        ldsEL[(ky * 17 + hrow) * 40 + ic] = lo;
      }
    }
    __syncthreads();
#pragma unroll
    for (int ky = 0; ky < 3; ++ky) {
#pragma unroll
      for (int kx = 0; kx < 3; ++kx) {
        int tap = ky * 3 + kx;
        half8 BH, BL;
        if (kx == 0) {
          BH = *reinterpret_cast<const half8*>(&ldsEH[(ky * 17 + n) * 40 + koff]);
          BL = *reinterpret_cast<const half8*>(&ldsEL[(ky * 17 + n) * 40 + koff]);
        } else if (kx == 1) {
          BH = *reinterpret_cast<const half8*>(&ldsOH[(ky * 16 + n) * 40 + koff]);
          BL = *reinterpret_cast<const half8*>(&ldsOL[(ky * 16 + n) * 40 + koff]);
        } else {
          BH = *reinterpret_cast<const half8*>(&ldsEH[(ky * 17 + n + 1) * 40 + koff]);
          BL = *reinterpret_cast<const half8*>(&ldsEL[(ky * 17 + n + 1) * 40 + koff]);
        }
#pragma unroll
        for (int j = 0; j < NOC; ++j) {
          half8 AH = wh8[(((tap)*OCt + (ocT0 + j)) * ktiles + kT) * 64 + l];
          half8 AL = wh8[(((9 + tap) * OCt + (ocT0 + j)) * ktiles + kT) * 64 + l];
          acc[j] = __builtin_amdgcn_mfma_f32_16x16x32_f16(AH, BH, acc[j], 0, 0, 0);
          acc[j] = __builtin_amdgcn_mfma_f32_16x16x32_f16(AH, BL, acc[j], 0, 0, 0);
          acc[j] = __builtin_amdgcn_mfma_f32_16x16x32_f16(AL, BH, acc[j], 0, 0, 0);
        }
      }
    }
  }
  int ox = px0 + n;
#pragma unroll
  for (int j = 0; j < NOC; ++j) {
    int oc0 = (ocT0 + j) * 16 + ((l >> 4) << 2);
#pragma unroll
    for (int r = 0; r < 4; ++r) {
      int oc = oc0 + r;
      float bv = bias[oc];
      size_t idx = ((size_t)oc * OH + oy) * OW + ox;
      float v32 = __fadd_rn(acc[j][r], bv);
      v32 = __fmul_rn(v32, kBNF);
      out[idx] = fmaxf(v32, 0.f);
    }
  }
}

// ---------------------------------------------------------------- 1x1 conv, fp32 acc (R15)
template <int S, bool RELU>
__global__ __launch_bounds__(256) void conv1x1_k(
    const float* __restrict__ in, const float* __restrict__ w,
    const float* __restrict__ bias, float* __restrict__ out,
    int IC, int IH, int IW, int OC, int OH, int OW) {
  __shared__ float in_s[16][64];
  __shared__ float w_s[16][64];
  const int P = OH * OW;
  int t = threadIdx.x;
  int p0 = blockIdx.x * 64;
  int oc0 = blockIdx.y * 64;
  int oc4 = (t >> 4) * 4, px4 = (t & 15) * 4;
  float acc[4][4] = {};
  for (int ic0 = 0; ic0 < IC; ic0 += 16) {
    __syncthreads();
    {
      int e = t;
#pragma unroll
      for (int k = 0; k < 4; ++k, e += 256) {
        int icr = e >> 6, pxr = e & 63;
        int p = p0 + pxr;
        float v = 0.f;
        if (p < P) {
          int oy = p / OW, ox = p % OW;
          v = in[((ic0 + icr) * IH + oy * S) * IW + ox * S];
        }
        in_s[icr][pxr] = v;
      }
      e = t;
#pragma unroll
      for (int k = 0; k < 4; ++k, e += 256) {
        int icr = e >> 6, ocr = e & 63;
        w_s[icr][ocr] = w[(oc0 + ocr) * IC + ic0 + icr];
      }
    }
    __syncthreads();
#pragma unroll
    for (int icr = 0; icr < 16; ++icr) {
      float4 iv = *reinterpret_cast<const float4*>(&in_s[icr][px4]);
      float4 wv = *reinterpret_cast<const float4*>(&w_s[icr][oc4]);
      const float* ip = (const float*)&iv;
      const float* wp = (const float*)&wv;
#pragma unroll
      for (int o = 0; o < 4; ++o)
#pragma unroll
        for (int p = 0; p < 4; ++p)
          acc[o][p] = fmaf(wp[o], ip[p], acc[o][p]);
    }
  }
  int p = p0 + px4;
  if (p < P) {
    int oy = p / OW, ox = p % OW;
#pragma unroll
    for (int o = 0; o < 4; ++o) {
      int oc = oc0 + oc4 + o;
      float bv = bias[oc];
      float4 rv;
      float* rp = (float*)&rv;
#pragma unroll
      for (int pp = 0; pp < 4; ++pp) {
        float v32 = __fadd_rn(acc[o][pp], bv);
        v32 = __fmul_rn(v32, kBNF);
        if (RELU) v32 = fmaxf(v32, 0.f);
        rp[pp] = v32;
      }
      *reinterpret_cast<float4*>(&out[((size_t)oc * OH + oy) * OW + ox]) = rv;
    }
  }
}

// ---------------------------------------------------------------- ConvT weight prep -> bf16 A-fragments (R14)
__global__ __launch_bounds__(256) void prep_wb_k(const float* __restrict__ w,
                                                 __hip_bfloat16* __restrict__ wb,
                                                 int IC, int OC) {
  int i = blockIdx.x * 256 + threadIdx.x;
  int total = 16 * IC * OC;
  if (i >= total) return;
  int per_cfg = IC * OC;
  int cfg = i / per_cfg;
  int r = i - cfg * per_cfg;
  int ktiles = IC >> 5;
  int ocT = r / (ktiles * 512);
  int r2 = r - ocT * (ktiles * 512);
  int kT = r2 >> 9;
  int f = r2 & 511;
  int lane = f >> 3, e = f & 7;
  int m = lane & 15, kk = ((lane >> 4) << 3) + e;
  int oc = ocT * 16 + m, ic = kT * 32 + kk;
  int kyb = cfg >> 3, ty = (cfg >> 2) & 1, kx = cfg & 3;
  int ky = kyb + 2 * ty;
  wb[i] = __float2bfloat16(w[((size_t)ic * OC + oc) * 16 + ky * 4 + kx]);
}

// ---------------------------------------------------------------- ConvT k4 s2 p1 via MFMA bf16 (R14, validated)
__global__ __launch_bounds__(256) void convt_mfma_k(
    const float* __restrict__ in, const __hip_bfloat16* __restrict__ wb,
    const float* __restrict__ bias, float* __restrict__ out,
    int IC, int IH, int IW, int OC, int OH, int OW) {
  __shared__ __align__(16) __hip_bfloat16 lds[2 * 18 * 40];
  int t = threadIdx.x;
  int wv = t >> 6, l = t & 63;
  int ox0 = blockIdx.x * 32;
  int oy = blockIdx.y;
  int oc0w = blockIdx.z * 64 + wv * 16;
  int kyb = (oy & 1) ? 0 : 1;
  int hb = ox0 >> 1;
  int iy0n = oy + 1 - kyb;
  int iy0 = iy0n >> 1;
  bool ok0 = (iy0 < IH);
  int iy1n = oy + 1 - kyb - 2;
  int iy1 = iy1n >> 1;
  bool ok1 = (iy1n >= 0) && (iy1 < IH);
  f32x4 accE = {0.f, 0.f, 0.f, 0.f};
  f32x4 accO = {0.f, 0.f, 0.f, 0.f};
  const int ktiles = IC >> 5;
  int n = l & 15, koff = (l >> 4) * 8;
  const short8* wb8 = reinterpret_cast<const short8*>(wb);
  int ocT = oc0w >> 4;
  const int OCt = OC >> 4;
  for (int kT = 0; kT < ktiles; ++kT) {
    __syncthreads();
    for (int e = t; e < 1152; e += 256) {
      int ic = e / 36;
      int r = e - ic * 36;
      int ty = r / 18, xi = r - ty * 18;
      int ix = hb - 1 + xi;
      int iy = ty ? iy1 : iy0;
      bool ok = ty ? ok1 : ok0;
      float v = 0.f;
      if (ok && ix >= 0 && ix < IW)
        v = in[((size_t)(kT * 32 + ic) * IH + iy) * IW + ix];
      lds[(ty * 18 + xi) * 40 + ic] = __float2bfloat16(v);
    }
    __syncthreads();
#pragma unroll
    for (int ty = 0; ty < 2; ++ty) {
      short8 A0 = wb8[((((kyb * 2 + ty) * 4 + 0) * OCt + ocT) * ktiles + kT) * 64 + l];
      short8 A1 = wb8[((((kyb * 2 + ty) * 4 + 1) * OCt + ocT) * ktiles + kT) * 64 + l];
      short8 A2 = wb8[((((kyb * 2 + ty) * 4 + 2) * OCt + ocT) * ktiles + kT) * 64 + l];
      short8 A3 = wb8[((((kyb * 2 + ty) * 4 + 3) * OCt + ocT) * ktiles + kT) * 64 + l];
      short8 b0 = *reinterpret_cast<const short8*>(&lds[(ty * 18 + 0 + n) * 40 + koff]);
      short8 b1 = *reinterpret_cast<const short8*>(&lds[(ty * 18 + 1 + n) * 40 + koff]);
      short8 b2 = *reinterpret_cast<const short8*>(&lds[(ty * 18 + 2 + n) * 40 + koff]);
      accE = __builtin_amdgcn_mfma_f32_16x16x32_bf16(A1, b1, accE, 0, 0, 0);
      accE = __builtin_amdgcn_mfma_f32_16x16x32_bf16(A3, b0, accE, 0, 0, 0);
      accO = __builtin_amdgcn_mfma_f32_16x16x32_bf16(A0, b2, accO, 0, 0, 0);
      accO = __builtin_amdgcn_mfma_f32_16x16x32_bf16(A2, b1, accO, 0, 0, 0);
    }
  }
  int ocr0 = oc0w + ((l >> 4) << 2);
  int oxE = ox0 + 2 * n;
  int oxO = ox0 + 1 + 2 * n;
#pragma unroll
  for (int r = 0; r < 4; ++r) {
    float bv = bias[ocr0 + r];
    size_t rowbase = ((size_t)(ocr0 + r) * OH + oy) * OW;
    out[rowbase + oxE] = fmaxf((accE[r] + bv) * kBNF, 0.f);
    out[rowbase + oxO] = fmaxf((accO[r] + bv) * kBNF, 0.f);
  }
}

// ---------------------------------------------------------------- final 3x3 conv 128->1 + sigmoid (R9)
__global__ __launch_bounds__(320) void dow_k(const float* __restrict__ in,
                                             const float* __restrict__ w,
                                             const float* __restrict__ bias,
                                             float* __restrict__ out) {
  const int H = 320, W = 320, IC = 128;
  int oy = blockIdx.x;
  int tx = threadIdx.x;
  __shared__ float in_s[4][3][W + 2];
  __shared__ float w_s[IC * 9];
  for (int e = tx; e < IC * 9; e += 320) w_s[e] = w[e];
  float acc = 0.f;
  for (int ic0 = 0; ic0 < IC; ic0 += 4) {
    __syncthreads();
    for (int e = tx; e < 4 * 3 * (W + 2); e += 320) {
      int icr = e / (3 * (W + 2));
      int rem = e - icr * (3 * (W + 2));
      int r = rem / (W + 2), c = rem - r * (W + 2);
      int iy = oy + r - 1, ix = c - 1;
      float v = 0.f;
      if (iy >= 0 && iy < H && ix >= 0 && ix < W)
        v = in[((ic0 + icr) * H + iy) * W + ix];
      in_s[icr][r][c] = v;
    }
    __syncthreads();
#pragma unroll
    for (int icr = 0; icr < 4; ++icr)
#pragma unroll
      for (int r = 0; r < 3; ++r)
#pragma unroll
        for (int c = 0; c < 3; ++c)
          acc = fmaf(w_s[(ic0 + icr) * 9 + r * 3 + c], in_s[icr][r][tx + c], acc);
  }
  acc += bias[0];
  out[oy * W + tx] = 1.f / (1.f + expf(-acc));
}

// ---------------------------------------------------------------- codebook sq-norms: numpy-pairwise fp32
__global__ __launch_bounds__(256) void cbprep_np(const float* __restrict__ cb,
                                                 float* __restrict__ c2f) {
  int e = blockIdx.x, t = threadIdx.x;
  __shared__ float a[256];
  a[t] = cb[e * 256 + t];
  __syncthreads();
  if (t == 0) {
    float tot = 0.f;
    for (int h = 0; h < 2; ++h) {
      const float* p = a + h * 128;
      float r[8];
#pragma unroll
      for (int j = 0; j < 8; ++j) r[j] = __fmul_rn(p[j], p[j]);
      for (int i = 8; i < 128; i += 8)
#pragma unroll
        for (int j = 0; j < 8; ++j) r[j] = __fadd_rn(r[j], __fmul_rn(p[i + j], p[i + j]));
      float s = __fadd_rn(__fadd_rn(__fadd_rn(r[0], r[1]), __fadd_rn(r[2], r[3])),
                          __fadd_rn(__fadd_rn(r[4], r[5]), __fadd_rn(r[6], r[7])));
      tot = (h == 0) ? s : __fadd_rn(tot, s);
    }
    c2f[e] = tot;
  }
}

// ---------------------------------------------------------------- VQ: 4 rows/block (R15, validated)
__global__ __launch_bounds__(256) void vq_ref_k(const float* __restrict__ z,
                                                const float* __restrict__ cb,
                                                const float* __restrict__ c2f,
                                                float* __restrict__ zq_out,
                                                float* __restrict__ idx_out) {
  int n0 = blockIdx.x * 4;
  int t = threadIdx.x;
  __shared__ float f[4][256];
  __shared__ float dist[4][1024];
  __shared__ float rr[4][2][8];
  __shared__ float f2s[4];
  __shared__ int bestIdx[4];
  for (int e = t; e < 1024; e += 256) {
    int r = e >> 8, c = e & 255;
    f[r][c] = z[(size_t)(n0 + r) * 256 + c];
  }
  __syncthreads();
  if (t < 64) {
    int row = t >> 4, hh = (t >> 3) & 1, j = t & 7;
    const float* p = f[row] + hh * 128;
    float r = __fmul_rn(p[j], p[j]);
    for (int i = 8; i < 128; i += 8) r = __fadd_rn(r, __fmul_rn(p[i + j], p[i + j]));
    rr[row][hh][j] = r;
  }
  __syncthreads();
  if (t < 4) {
    float s0 = __fadd_rn(__fadd_rn(__fadd_rn(rr[t][0][0], rr[t][0][1]), __fadd_rn(rr[t][0][2], rr[t][0][3])),
                         __fadd_rn(__fadd_rn(rr[t][0][4], rr[t][0][5]), __fadd_rn(rr[t][0][6], rr[t][0][7])));
    float s1 = __fadd_rn(__fadd_rn(__fadd_rn(rr[t][1][0], rr[t][1][1]), __fadd_rn(rr[t][1][2], rr[t][1][3])),
                         __fadd_rn(__fadd_rn(rr[t][1][4], rr[t][1][5]), __fadd_rn(rr[t][1][6], rr[t][1][7])));
    f2s[t] = __fadd_rn(s0, s1);
  }
  __syncthreads();
  for (int e = t; e < 1024; e += 256) {
    const float4* cbe = reinterpret_cast<const float4*>(cb + (size_t)e * 256);
    double d0 = 0.0, d1 = 0.0, d2 = 0.0, d3 = 0.0;
    for (int d = 0; d < 64; ++d) {
      float4 c4 = cbe[d];
      float4 f0 = *reinterpret_cast<const float4*>(&f[0][d * 4]);
      float4 f1 = *reinterpret_cast<const float4*>(&f[1][d * 4]);
      float4 f2v = *reinterpret_cast<const float4*>(&f[2][d * 4]);
      float4 f3 = *reinterpret_cast<const float4*>(&f[3][d * 4]);
      d0 = fma((double)f0.x, (double)c4.x, d0); d0 = fma((double)f0.y, (double)c4.y, d0);
      d0 = fma((double)f0.z, (double)c4.z, d0); d0 = fma((double)f0.w, (double)c4.w, d0);
      d1 = fma((double)f1.x, (double)c4.x, d1); d1 = fma((double)f1.y, (double)c4.y, d1);
      d1 = fma((double)f1.z, (double)c4.z, d1); d1 = fma((double)f1.w, (double)c4.w, d1);
      d2 = fma((double)f2v.x, (double)c4.x, d2); d2 = fma((double)f2v.y, (double)c4.y, d2);
      d2 = fma((double)f2v.z, (double)c4.z, d2); d2 = fma((double)f2v.w, (double)c4.w, d2);
      d3 = fma((double)f3.x, (double)c4.x, d3); d3 = fma((double)f3.y, (double)c4.y, d3);
      d3 = fma((double)f3.z, (double)c4.z, d3); d3 = fma((double)f3.w, (double)c4.w, d3);
    }
    float c2e = c2f[e];
    dist[0][e] = __fsub_rn(__fadd_rn(f2s[0], c2e), __fmul_rn(2.f, (float)d0));
    dist[1][e] = __fsub_rn(__fadd_rn(f2s[1], c2e), __fmul_rn(2.f, (float)d1));
    dist[2][e] = __fsub_rn(__fadd_rn(f2s[2], c2e), __fmul_rn(2.f, (float)d2));
    dist[3][e] = __fsub_rn(__fadd_rn(f2s[3], c2e), __fmul_rn(2.f, (float)d3));
  }
  __syncthreads();
  {
    int row = t >> 6, l = t & 63;
    float bv = dist[row][l];
    int bi = l;
    for (int e = l + 64; e < 1024; e += 64) {
      float v = dist[row][e];
      if (v < bv) { bv = v; bi = e; }
    }
#pragma unroll
    for (int m = 1; m < 64; m <<= 1) {
      float ov = __shfl_xor(bv, m, 64);
      int oi = __shfl_xor(bi, m, 64);
      if (ov < bv || (ov == bv && oi < bi)) { bv = ov; bi = oi; }
    }
    if (l == 0) {
      bestIdx[row] = bi;
      idx_out[n0 + row] = (float)bi;
    }
  }
  __syncthreads();
#pragma unroll
  for (int r = 0; r < 4; ++r)
    zq_out[(size_t)(n0 + r) * 256 + t] = cb[(size_t)bestIdx[r] * 256 + t];
}

// ================================================================ host
extern "C" void kernel_launch(void* const* d_in, const int* in_sizes, int n_in,
                              void* d_out, int out_size, void* d_ws, size_t ws_size,
                              hipStream_t stream) {
  const float* x = (const float*)d_in[0];
  const float* w0 = (const float*)d_in[1];
  const float* b0 = (const float*)d_in[2];
  const float* a_c1w = (const float*)d_in[3];
  const float* a_c1b = (const float*)d_in[4];
  const float* a_c2w = (const float*)d_in[5];
  const float* a_c2b = (const float*)d_in[6];
  const float* a_scw = (const float*)d_in[7];
  const float* a_scb = (const float*)d_in[8];
  const float* b_c1w = (const float*)d_in[9];
  const float* b_c1b = (const float*)d_in[10];
  const float* b_c2w = (const float*)d_in[11];
  const float* b_c2b = (const float*)d_in[12];
  const float* b_scw = (const float*)d_in[13];
  const float* b_scb = (const float*)d_in[14];
  const float* ew = (const float*)d_in[15];
  const float* eb = (const float*)d_in[16];
  const float* cb = (const float*)d_in[17];
  const float* d0w = (const float*)d_in[18];
  const float* d0b = (const float*)d_in[19];
  const float* dt1w = (const float*)d_in[20];
  const float* dt1b = (const float*)d_in[21];
  const float* dt2w = (const float*)d_in[22];
  const float* dt2b = (const float*)d_in[23];
  const float* doww = (const float*)d_in[24];
  const float* dob = (const float*)d_in[25];

  // ws (floats): A 13.1M | B 6.55M | C 6.55M | c2f 1024  ~= 105 MB (unchanged)
  float* ws = (float*)d_ws;
  float* A = ws;
  float* Bf = ws + 13107200;
  float* Cf = ws + 19660800;
  float* c2f = ws + 26214400;
  _Float16* wh_ac1 = (_Float16*)(void*)Cf;
  _Float16* wh_bc1 = (_Float16*)(void*)(Bf + 3300000);
  _Float16* wh_ac2 = (_Float16*)(void*)(A + 6600000);
  _Float16* wh_bc2 = (_Float16*)(void*)(A + 3300000);
  __hip_bfloat16* wb_dt1 = (__hip_bfloat16*)(void*)A;
  __hip_bfloat16* wb_dt2 = (__hip_bfloat16*)(void*)(Bf + 3400000);

  float* outf = (float*)d_out;
  float* recon = outf;
  float* zq = outf + 409600;
  float* idxo = zq + 6553600;

  cbprep_np<<<1024, 256, 0, stream>>>(cb, c2f);

  for (int b = 0; b < 4; ++b) {
    const float* xb = x + (size_t)b * 102400;
    float* zqb = zq + (size_t)b * 1638400;
    float* idxb = idxo + (size_t)b * 6400;
    float* reconb = recon + (size_t)b * 102400;

    // encoder (all 3x3 layers via fp16-split MFMA, NOC=2)
    conv0_k<<<320, 320, 0, stream>>>(xb, w0, b0, A);
    prep_w3h_k<<<2304, 256, 0, stream>>>(a_c1w, wh_ac1, 128, 256);
    conv3s2_mfma_k<2><<<dim3(10, 160, 2), 256, 0, stream>>>(
        A, wh_ac1, a_c1b, Bf, 128, 320, 320, 256, 160, 160);
    conv1x1_k<2, false><<<dim3(400, 4), 256, 0, stream>>>(
        A, a_scw, a_scb, Cf, 128, 320, 320, 256, 160, 160);
    prep_w3h_k<<<4608, 256, 0, stream>>>(a_c2w, wh_ac2, 256, 256);
    conv3s1_mfma_k<2><<<dim3(10, 160, 2), 256, 0, stream>>>(
        Bf, wh_ac2, a_c2b, Cf, A, 256, 160, 256);
    prep_w3h_k<<<9216, 256, 0, stream>>>(b_c1w, wh_bc1, 256, 512);
    conv3s2_mfma_k<2><<<dim3(5, 80, 4), 256, 0, stream>>>(
        A, wh_bc1, b_c1b, Bf, 256, 160, 160, 512, 80, 80);
    conv1x1_k<2, false><<<dim3(100, 8), 256, 0, stream>>>(
        A, b_scw, b_scb, Cf, 256, 160, 160, 512, 80, 80);
    prep_w3h_k<<<18432, 256, 0, stream>>>(b_c2w, wh_bc2, 512, 512);
    conv3s1_mfma_k<2><<<dim3(5, 80, 4), 256, 0, stream>>>(
        Bf, wh_bc2, b_c2b, Cf, A, 512, 80, 512);
    conv1x1_k<1, false><<<dim3(100, 4), 256, 0, stream>>>(
        A, ew, eb, Cf, 512, 80, 80, 256, 80, 80);
    // VQ
    vq_ref_k<<<1600, 256, 0, stream>>>(Cf, cb, c2f, zqb, idxb);
    // decoder: bf16 MFMA ConvT (R14)
    prep_wb_k<<<8192, 256, 0, stream>>>(dt1w, wb_dt1, 512, 256);
    prep_wb_k<<<2048, 256, 0, stream>>>(dt2w, wb_dt2, 256, 128);
    conv1x1_k<1, true><<<dim3(100, 8), 256, 0, stream>>>(
        zqb, d0w, d0b, Bf, 256, 80, 80, 512, 80, 80);
    convt_mfma_k<<<dim3(5, 160, 4), 256, 0, stream>>>(
        Bf, wb_dt1, dt1b, Cf, 512, 80, 80, 256, 160, 160);
    convt_mfma_k<<<dim3(10, 320, 2), 256, 0, stream>>>(
        Cf, wb_dt2, dt2b, A, 256, 160, 160, 128, 320, 320);
    dow_k<<<320, 320, 0, stream>>>(A, doww, dob, reconb);
  }
}

// Round 24
// 6484.035 us; speedup vs baseline: 1.2780x; 1.0072x over previous
//
#include <hip/hip_runtime.h>
#include <hip/hip_bf16.h>
#include <math.h>

// Round 24: R21 z-chain EXACTLY (a_sc/b_sc/e on fp32 conv1x1_k — shortcut/e
// layers are the empirically flip-sensitive set per R22/R23 probes) + d0 on
// fp16-split MFMA (decoder-only; provably cannot affect indices).
// Diagnostic: absmax == 3.814697e-06 guaranteed (z bit-identical to R21).

static constexpr float kBNF = 0.9999950000374997f;

typedef short short8 __attribute__((ext_vector_type(8)));
typedef _Float16 half8 __attribute__((ext_vector_type(8)));
typedef float f32x4 __attribute__((ext_vector_type(4)));

// ---------------------------------------------------------------- conv0: 1->128, 3x3, s1, relu (B=1), fp32
__global__ __launch_bounds__(320) void conv0_k(const float* __restrict__ x,
                                               const float* __restrict__ w,
                                               const float* __restrict__ b,
                                               float* __restrict__ out) {
  const int H = 320, W = 320, OC = 128;
  int oy = blockIdx.x;
  int tx = threadIdx.x;
  __shared__ float in_s[3][W + 2];
  __shared__ float w_s[128 * 9];
  __shared__ float b_s[128];
  for (int e = tx; e < 3 * (W + 2); e += 320) {
    int r = e / (W + 2), c = e % (W + 2);
    int iy = oy + r - 1, ix = c - 1;
    float v = 0.f;
    if (iy >= 0 && iy < H && ix >= 0 && ix < W) v = x[iy * W + ix];
    in_s[r][c] = v;
  }
  for (int e = tx; e < 128 * 9; e += 320) w_s[e] = w[e];
  for (int e = tx; e < 128; e += 320) b_s[e] = b[e];
  __syncthreads();
  float iv[9];
#pragma unroll
  for (int r = 0; r < 3; ++r)
#pragma unroll
    for (int c = 0; c < 3; ++c) iv[r * 3 + c] = in_s[r][tx + c];
  for (int oc = 0; oc < OC; ++oc) {
    float acc = 0.f;
#pragma unroll
    for (int t = 0; t < 9; ++t) acc = fmaf(w_s[oc * 9 + t], iv[t], acc);
    float v32 = __fadd_rn(acc, b_s[oc]);
    v32 = __fmul_rn(v32, kBNF);
    out[(oc * H + oy) * W + tx] = fmaxf(v32, 0.f);
  }
}

// ---------------------------------------------------------------- conv3x3 weight prep -> fp16-split A-frags
__global__ __launch_bounds__(256) void prep_w3h_k(const float* __restrict__ w,
                                                  _Float16* __restrict__ wh,
                                                  int IC, int OC) {
  int i = blockIdx.x * 256 + threadIdx.x;
  int total = 2 * 9 * IC * OC;
  if (i >= total) return;
  int e = i & 7;
  int lane = (i >> 3) & 63;
  int rest = i >> 9;
  int ktiles = IC >> 5;
  int kT = rest % ktiles;
  int rest2 = rest / ktiles;
  int OCt = OC >> 4;
  int ocT = rest2 % OCt;
  int rest3 = rest2 / OCt;
  int tap = rest3 % 9;
  int split = rest3 / 9;
  int m = lane & 15, k = ((lane >> 4) << 3) + e;
  int oc = ocT * 16 + m, ic = kT * 32 + k;
  float v = w[((size_t)oc * IC + ic) * 9 + tap];
  _Float16 hi = (_Float16)v;
  wh[i] = (split == 0) ? hi : (_Float16)(v - (float)hi);
}

// ---------------------------------------------------------------- 1x1 conv weight prep -> fp16-split A-frags (d0)
__global__ __launch_bounds__(256) void prep_w1h_k(const float* __restrict__ w,
                                                  _Float16* __restrict__ wh,
                                                  int IC, int OC) {
  int i = blockIdx.x * 256 + threadIdx.x;
  int total = 2 * IC * OC;
  if (i >= total) return;
  int e = i & 7;
  int lane = (i >> 3) & 63;
  int rest = i >> 9;
  int ktiles = IC >> 5;
  int kT = rest % ktiles;
  int rest2 = rest / ktiles;
  int OCt = OC >> 4;
  int ocT = rest2 % OCt;
  int split = rest2 / OCt;
  int m = lane & 15, k = ((lane >> 4) << 3) + e;
  int oc = ocT * 16 + m, ic = kT * 32 + k;
  float v = w[(size_t)oc * IC + ic];
  _Float16 hi = (_Float16)v;
  wh[i] = (split == 0) ? hi : (_Float16)(v - (float)hi);
}

// ---------------------------------------------------------------- 1x1 conv via MFMA fp16-split (d0 only)
template <int S, bool RELU, int NOC>
__global__ __launch_bounds__(256) void conv1x1_mfma_k(
    const float* __restrict__ in, const _Float16* __restrict__ wh,
    const float* __restrict__ bias, float* __restrict__ out,
    int IC, int IH, int IW, int OC, int OH, int OW) {
  __shared__ __align__(16) _Float16 ldsH[64 * 40];
  __shared__ __align__(16) _Float16 ldsL[64 * 40];
  int t = threadIdx.x;
  int wv = t >> 6, l = t & 63;
  int px0 = blockIdx.x * 64;
  int ocT0 = blockIdx.y * NOC;
  const int P = OH * OW;
  const int ktiles = IC >> 5;
  const int OCt = OC >> 4;
  int n = l & 15, koff = (l >> 4) * 8;
  f32x4 acc[NOC];
#pragma unroll
  for (int j = 0; j < NOC; ++j) acc[j] = {0.f, 0.f, 0.f, 0.f};
  const half8* wh8 = reinterpret_cast<const half8*>(wh);
  for (int kT = 0; kT < ktiles; ++kT) {
    __syncthreads();
    for (int e = t; e < 2048; e += 256) {
      int pr = e & 63, ic = e >> 6;
      int p = px0 + pr;
      float v;
      if (S == 1) {
        v = in[(size_t)(kT * 32 + ic) * P + p];
      } else {
        int oy = p / OW, ox = p % OW;
        v = in[((size_t)(kT * 32 + ic) * IH + oy * S) * IW + ox * S];
      }
      _Float16 hi = (_Float16)v;
      ldsH[pr * 40 + ic] = hi;
      ldsL[pr * 40 + ic] = (_Float16)(v - (float)hi);
    }
    __syncthreads();
    half8 BH = *reinterpret_cast<const half8*>(&ldsH[(wv * 16 + n) * 40 + koff]);
    half8 BL = *reinterpret_cast<const half8*>(&ldsL[(wv * 16 + n) * 40 + koff]);
#pragma unroll
    for (int j = 0; j < NOC; ++j) {
      half8 AH = wh8[((0 * OCt + (ocT0 + j)) * ktiles + kT) * 64 + l];
      half8 AL = wh8[((1 * OCt + (ocT0 + j)) * ktiles + kT) * 64 + l];
      acc[j] = __builtin_amdgcn_mfma_f32_16x16x32_f16(AH, BH, acc[j], 0, 0, 0);
      acc[j] = __builtin_amdgcn_mfma_f32_16x16x32_f16(AH, BL, acc[j], 0, 0, 0);
      acc[j] = __builtin_amdgcn_mfma_f32_16x16x32_f16(AL, BH, acc[j], 0, 0, 0);
    }
  }
  int p = px0 + wv * 16 + n;
#pragma unroll
  for (int j = 0; j < NOC; ++j) {
    int oc0 = (ocT0 + j) * 16 + ((l >> 4) << 2);
#pragma unroll
    for (int r = 0; r < 4; ++r) {
      int oc = oc0 + r;
      float bv = bias[oc];
      float v32 = __fadd_rn(acc[j][r], bv);
      v32 = __fmul_rn(v32, kBNF);
      if (RELU) v32 = fmaxf(v32, 0.f);
      out[(size_t)oc * P + p] = v32;
    }
  }
}

// ---------------------------------------------------------------- 1x1 conv fp32 (a_sc / b_sc / e; R21-proven)
template <int S, bool RELU>
__global__ __launch_bounds__(256) void conv1x1_k(
    const float* __restrict__ in, const float* __restrict__ w,
    const float* __restrict__ bias, float* __restrict__ out,
    int IC, int IH, int IW, int OC, int OH, int OW) {
  __shared__ float in_s[16][64];
  __shared__ float w_s[16][64];
  const int P = OH * OW;
  int t = threadIdx.x;
  int p0 = blockIdx.x * 64;
  int oc0 = blockIdx.y * 64;
  int oc4 = (t >> 4) * 4, px4 = (t & 15) * 4;
  float acc[4][4] = {};
  for (int ic0 = 0; ic0 < IC; ic0 += 16) {
    __syncthreads();
    {
      int e = t;
#pragma unroll
      for (int k = 0; k < 4; ++k, e += 256) {
        int icr = e >> 6, pxr = e & 63;
        int p = p0 + pxr;
        float v = 0.f;
        if (p < P) {
          int oy = p / OW, ox = p % OW;
          v = in[((ic0 + icr) * IH + oy * S) * IW + ox * S];
        }
        in_s[icr][pxr] = v;
      }
      e = t;
#pragma unroll
      for (int k = 0; k < 4; ++k, e += 256) {
        int icr = e >> 6, ocr = e & 63;
        w_s[icr][ocr] = w[(oc0 + ocr) * IC + ic0 + icr];
      }
    }
    __syncthreads();
#pragma unroll
    for (int icr = 0; icr < 16; ++icr) {
      float4 iv = *reinterpret_cast<const float4*>(&in_s[icr][px4]);
      float4 wv = *reinterpret_cast<const float4*>(&w_s[icr][oc4]);
      const float* ip = (const float*)&iv;
      const float* wp = (const float*)&wv;
#pragma unroll
      for (int o = 0; o < 4; ++o)
#pragma unroll
        for (int p = 0; p < 4; ++p)
          acc[o][p] = fmaf(wp[o], ip[p], acc[o][p]);
    }
  }
  int p = p0 + px4;
  if (p < P) {
    int oy = p / OW, ox = p % OW;
#pragma unroll
    for (int o = 0; o < 4; ++o) {
      int oc = oc0 + oc4 + o;
      float bv = bias[oc];
      float4 rv;
      float* rp = (float*)&rv;
#pragma unroll
      for (int pp = 0; pp < 4; ++pp) {
        float v32 = __fadd_rn(acc[o][pp], bv);
        v32 = __fmul_rn(v32, kBNF);
        if (RELU) v32 = fmaxf(v32, 0.f);
        rp[pp] = v32;
      }
      *reinterpret_cast<float4*>(&out[((size_t)oc * OH + oy) * OW + ox]) = rv;
    }
  }
}

// ---------------------------------------------------------------- 3x3 conv S=1 via MFMA fp16-split, NOC ocT/wave
template <int NOC>
__global__ __launch_bounds__(256) void conv3s1_mfma_k(
    const float* __restrict__ in, const _Float16* __restrict__ wh,
    const float* __restrict__ bias, const float* __restrict__ skip,
    float* __restrict__ out, int IC, int HW_, int OC) {
  __shared__ __align__(16) _Float16 ldsH[3 * 20 * 40];
  __shared__ __align__(16) _Float16 ldsL[3 * 20 * 40];
  int t = threadIdx.x;
  int wv = t >> 6, l = t & 63;
  int px0 = blockIdx.x * 16;
  int oy = blockIdx.y;
  int ocT0 = (blockIdx.z * 4 + wv) * NOC;
  const int ktiles = IC >> 5;
  const int OCt = OC >> 4;
  int n = l & 15, koff = (l >> 4) * 8;
  f32x4 acc[NOC];
#pragma unroll
  for (int j = 0; j < NOC; ++j) acc[j] = {0.f, 0.f, 0.f, 0.f};
  const half8* wh8 = reinterpret_cast<const half8*>(wh);
  for (int kT = 0; kT < ktiles; ++kT) {
    __syncthreads();
    for (int e = t; e < 1728; e += 256) {
      int xi = e % 18;
      int rem = e / 18;
      int ic = rem & 31, r = rem >> 5;
      int iy = oy - 1 + r;
      int ix = px0 - 1 + xi;
      float v = 0.f;
      if (iy >= 0 && iy < HW_ && ix >= 0 && ix < HW_)
        v = in[((size_t)(kT * 32 + ic) * HW_ + iy) * HW_ + ix];
      _Float16 hi = (_Float16)v;
      ldsH[(r * 20 + xi) * 40 + ic] = hi;
      ldsL[(r * 20 + xi) * 40 + ic] = (_Float16)(v - (float)hi);
    }
    __syncthreads();
#pragma unroll
    for (int ky = 0; ky < 3; ++ky) {
#pragma unroll
      for (int kx = 0; kx < 3; ++kx) {
        int tap = ky * 3 + kx;
        half8 BH = *reinterpret_cast<const half8*>(&ldsH[(ky * 20 + n + kx) * 40 + koff]);
        half8 BL = *reinterpret_cast<const half8*>(&ldsL[(ky * 20 + n + kx) * 40 + koff]);
#pragma unroll
        for (int j = 0; j < NOC; ++j) {
          half8 AH = wh8[(((tap)*OCt + (ocT0 + j)) * ktiles + kT) * 64 + l];
          half8 AL = wh8[(((9 + tap) * OCt + (ocT0 + j)) * ktiles + kT) * 64 + l];
          acc[j] = __builtin_amdgcn_mfma_f32_16x16x32_f16(AH, BH, acc[j], 0, 0, 0);
          acc[j] = __builtin_amdgcn_mfma_f32_16x16x32_f16(AH, BL, acc[j], 0, 0, 0);
          acc[j] = __builtin_amdgcn_mfma_f32_16x16x32_f16(AL, BH, acc[j], 0, 0, 0);
        }
      }
    }
  }
  int ox = px0 + n;
#pragma unroll
  for (int j = 0; j < NOC; ++j) {
    int oc0 = (ocT0 + j) * 16 + ((l >> 4) << 2);
#pragma unroll
    for (int r = 0; r < 4; ++r) {
      int oc = oc0 + r;
      float bv = bias[oc];
      size_t idx = ((size_t)oc * HW_ + oy) * HW_ + ox;
      float v32 = __fadd_rn(acc[j][r], bv);
      v32 = __fmul_rn(v32, kBNF);
      v32 = __fadd_rn(v32, skip[idx]);
      out[idx] = fmaxf(v32, 0.f);
    }
  }
}

// ---------------------------------------------------------------- 3x3 conv S=2 via MFMA fp16-split, parity LDS, NOC
template <int NOC>
__global__ __launch_bounds__(256) void conv3s2_mfma_k(
    const float* __restrict__ in, const _Float16* __restrict__ wh,
    const float* __restrict__ bias, float* __restrict__ out,
    int IC, int IH, int IW, int OC, int OH, int OW) {
  __shared__ __align__(16) _Float16 ldsEH[3 * 17 * 40];
  __shared__ __align__(16) _Float16 ldsEL[3 * 17 * 40];
  __shared__ __align__(16) _Float16 ldsOH[3 * 16 * 40];
  __shared__ __align__(16) _Float16 ldsOL[3 * 16 * 40];
  int t = threadIdx.x;
  int wv = t >> 6, l = t & 63;
  int px0 = blockIdx.x * 16;
  int oy = blockIdx.y;
  int ocT0 = (blockIdx.z * 4 + wv) * NOC;
  const int ktiles = IC >> 5;
  const int OCt = OC >> 4;
  int n = l & 15, koff = (l >> 4) * 8;
  f32x4 acc[NOC];
#pragma unroll
  for (int j = 0; j < NOC; ++j) acc[j] = {0.f, 0.f, 0.f, 0.f};
  const half8* wh8 = reinterpret_cast<const half8*>(wh);
  for (int kT = 0; kT < ktiles; ++kT) {
    __syncthreads();
    for (int e = t; e < 3168; e += 256) {
      int ic = e & 31;
      int rem = e >> 5;
      int xi = rem % 33, ky = rem / 33;
      int iy = oy * 2 - 1 + ky;
      int ix = px0 * 2 - 1 + xi;
      float v = 0.f;
      if (iy >= 0 && iy < IH && ix >= 0 && ix < IW)
        v = in[((size_t)(kT * 32 + ic) * IH + iy) * IW + ix];
      _Float16 hi = (_Float16)v;
      _Float16 lo = (_Float16)(v - (float)hi);
      int hrow = xi >> 1;
      if (xi & 1) {
        ldsOH[(ky * 16 + hrow) * 40 + ic] = hi;
        ldsOL[(ky * 16 + hrow) * 40 + ic] = lo;
      } else {
        ldsEH[(ky * 17 + hrow) * 40 + ic] = hi;
        ldsEL[(ky * 17 + hrow) * 40 + ic] = lo;
      }
    }
    __syncthreads();
#pragma unroll
    for (int ky = 0; ky < 3; ++ky) {
#pragma unroll
      for (int kx = 0; kx < 3; ++kx) {
        int tap = ky * 3 + kx;
        half8 BH, BL;
        if (kx == 0) {
          BH = *reinterpret_cast<const half8*>(&ldsEH[(ky * 17 + n) * 40 + koff]);
          BL = *reinterpret_cast<const half8*>(&ldsEL[(ky * 17 + n) * 40 + koff]);
        } else if (kx == 1) {
          BH = *reinterpret_cast<const half8*>(&ldsOH[(ky * 16 + n) * 40 + koff]);
          BL = *reinterpret_cast<const half8*>(&ldsOL[(ky * 16 + n) * 40 + koff]);
        } else {
          BH = *reinterpret_cast<const half8*>(&ldsEH[(ky * 17 + n + 1) * 40 + koff]);
          BL = *reinterpret_cast<const half8*>(&ldsEL[(ky * 17 + n + 1) * 40 + koff]);
        }
#pragma unroll
        for (int j = 0; j < NOC; ++j) {
          half8 AH = wh8[(((tap)*OCt + (ocT0 + j)) * ktiles + kT) * 64 + l];
          half8 AL = wh8[(((9 + tap) * OCt + (ocT0 + j)) * ktiles + kT) * 64 + l];
          acc[j] = __builtin_amdgcn_mfma_f32_16x16x32_f16(AH, BH, acc[j], 0, 0, 0);
          acc[j] = __builtin_amdgcn_mfma_f32_16x16x32_f16(AH, BL, acc[j], 0, 0, 0);
          acc[j] = __builtin_amdgcn_mfma_f32_16x16x32_f16(AL, BH, acc[j], 0, 0, 0);
        }
      }
    }
  }
  int ox = px0 + n;
#pragma unroll
  for (int j = 0; j < NOC; ++j) {
    int oc0 = (ocT0 + j) * 16 + ((l >> 4) << 2);
#pragma unroll
    for (int r = 0; r < 4; ++r) {
      int oc = oc0 + r;
      float bv = bias[oc];
      size_t idx = ((size_t)oc * OH + oy) * OW + ox;
      float v32 = __fadd_rn(acc[j][r], bv);
      v32 = __fmul_rn(v32, kBNF);
      out[idx] = fmaxf(v32, 0.f);
    }
  }
}

// ---------------------------------------------------------------- ConvT weight prep -> bf16 A-fragments (R14)
__global__ __launch_bounds__(256) void prep_wb_k(const float* __restrict__ w,
                                                 __hip_bfloat16* __restrict__ wb,
                                                 int IC, int OC) {
  int i = blockIdx.x * 256 + threadIdx.x;
  int total = 16 * IC * OC;
  if (i >= total) return;
  int per_cfg = IC * OC;
  int cfg = i / per_cfg;
  int r = i - cfg * per_cfg;
  int ktiles = IC >> 5;
  int ocT = r / (ktiles * 512);
  int r2 = r - ocT * (ktiles * 512);
  int kT = r2 >> 9;
  int f = r2 & 511;
  int lane = f >> 3, e = f & 7;
  int m = lane & 15, kk = ((lane >> 4) << 3) + e;
  int oc = ocT * 16 + m, ic = kT * 32 + kk;
  int kyb = cfg >> 3, ty = (cfg >> 2) & 1, kx = cfg & 3;
  int ky = kyb + 2 * ty;
  wb[i] = __float2bfloat16(w[((size_t)ic * OC + oc) * 16 + ky * 4 + kx]);
}

// ---------------------------------------------------------------- ConvT k4 s2 p1 via MFMA bf16 (R14, validated)
__global__ __launch_bounds__(256) void convt_mfma_k(
    const float* __restrict__ in, const __hip_bfloat16* __restrict__ wb,
    const float* __restrict__ bias, float* __restrict__ out,
    int IC, int IH, int IW, int OC, int OH, int OW) {
  __shared__ __align__(16) __hip_bfloat16 lds[2 * 18 * 40];
  int t = threadIdx.x;
  int wv = t >> 6, l = t & 63;
  int ox0 = blockIdx.x * 32;
  int oy = blockIdx.y;
  int oc0w = blockIdx.z * 64 + wv * 16;
  int kyb = (oy & 1) ? 0 : 1;
  int hb = ox0 >> 1;
  int iy0n = oy + 1 - kyb;
  int iy0 = iy0n >> 1;
  bool ok0 = (iy0 < IH);
  int iy1n = oy + 1 - kyb - 2;
  int iy1 = iy1n >> 1;
  bool ok1 = (iy1n >= 0) && (iy1 < IH);
  f32x4 accE = {0.f, 0.f, 0.f, 0.f};
  f32x4 accO = {0.f, 0.f, 0.f, 0.f};
  const int ktiles = IC >> 5;
  int n = l & 15, koff = (l >> 4) * 8;
  const short8* wb8 = reinterpret_cast<const short8*>(wb);
  int ocT = oc0w >> 4;
  const int OCt = OC >> 4;
  for (int kT = 0; kT < ktiles; ++kT) {
    __syncthreads();
    for (int e = t; e < 1152; e += 256) {
      int ic = e / 36;
      int r = e - ic * 36;
      int ty = r / 18, xi = r - ty * 18;
      int ix = hb - 1 + xi;
      int iy = ty ? iy1 : iy0;
      bool ok = ty ? ok1 : ok0;
      float v = 0.f;
      if (ok && ix >= 0 && ix < IW)
        v = in[((size_t)(kT * 32 + ic) * IH + iy) * IW + ix];
      lds[(ty * 18 + xi) * 40 + ic] = __float2bfloat16(v);
    }
    __syncthreads();
#pragma unroll
    for (int ty = 0; ty < 2; ++ty) {
      short8 A0 = wb8[((((kyb * 2 + ty) * 4 + 0) * OCt + ocT) * ktiles + kT) * 64 + l];
      short8 A1 = wb8[((((kyb * 2 + ty) * 4 + 1) * OCt + ocT) * ktiles + kT) * 64 + l];
      short8 A2 = wb8[((((kyb * 2 + ty) * 4 + 2) * OCt + ocT) * ktiles + kT) * 64 + l];
      short8 A3 = wb8[((((kyb * 2 + ty) * 4 + 3) * OCt + ocT) * ktiles + kT) * 64 + l];
      short8 b0 = *reinterpret_cast<const short8*>(&lds[(ty * 18 + 0 + n) * 40 + koff]);
      short8 b1 = *reinterpret_cast<const short8*>(&lds[(ty * 18 + 1 + n) * 40 + koff]);
      short8 b2 = *reinterpret_cast<const short8*>(&lds[(ty * 18 + 2 + n) * 40 + koff]);
      accE = __builtin_amdgcn_mfma_f32_16x16x32_bf16(A1, b1, accE, 0, 0, 0);
      accE = __builtin_amdgcn_mfma_f32_16x16x32_bf16(A3, b0, accE, 0, 0, 0);
      accO = __builtin_amdgcn_mfma_f32_16x16x32_bf16(A0, b2, accO, 0, 0, 0);
      accO = __builtin_amdgcn_mfma_f32_16x16x32_bf16(A2, b1, accO, 0, 0, 0);
    }
  }
  int ocr0 = oc0w + ((l >> 4) << 2);
  int oxE = ox0 + 2 * n;
  int oxO = ox0 + 1 + 2 * n;
#pragma unroll
  for (int r = 0; r < 4; ++r) {
    float bv = bias[ocr0 + r];
    size_t rowbase = ((size_t)(ocr0 + r) * OH + oy) * OW;
    out[rowbase + oxE] = fmaxf((accE[r] + bv) * kBNF, 0.f);
    out[rowbase + oxO] = fmaxf((accO[r] + bv) * kBNF, 0.f);
  }
}

// ---------------------------------------------------------------- final 3x3 conv 128->1 + sigmoid (R9)
__global__ __launch_bounds__(320) void dow_k(const float* __restrict__ in,
                                             const float* __restrict__ w,
                                             const float* __restrict__ bias,
                                             float* __restrict__ out) {
  const int H = 320, W = 320, IC = 128;
  int oy = blockIdx.x;
  int tx = threadIdx.x;
  __shared__ float in_s[4][3][W + 2];
  __shared__ float w_s[IC * 9];
  for (int e = tx; e < IC * 9; e += 320) w_s[e] = w[e];
  float acc = 0.f;
  for (int ic0 = 0; ic0 < IC; ic0 += 4) {
    __syncthreads();
    for (int e = tx; e < 4 * 3 * (W + 2); e += 320) {
      int icr = e / (3 * (W + 2));
      int rem = e - icr * (3 * (W + 2));
      int r = rem / (W + 2), c = rem - r * (W + 2);
      int iy = oy + r - 1, ix = c - 1;
      float v = 0.f;
      if (iy >= 0 && iy < H && ix >= 0 && ix < W)
        v = in[((ic0 + icr) * H + iy) * W + ix];
      in_s[icr][r][c] = v;
    }
    __syncthreads();
#pragma unroll
    for (int icr = 0; icr < 4; ++icr)
#pragma unroll
      for (int r = 0; r < 3; ++r)
#pragma unroll
        for (int c = 0; c < 3; ++c)
          acc = fmaf(w_s[(ic0 + icr) * 9 + r * 3 + c], in_s[icr][r][tx + c], acc);
  }
  acc += bias[0];
  out[oy * W + tx] = 1.f / (1.f + expf(-acc));
}

// ---------------------------------------------------------------- codebook sq-norms: numpy-pairwise fp32
__global__ __launch_bounds__(256) void cbprep_np(const float* __restrict__ cb,
                                                 float* __restrict__ c2f) {
  int e = blockIdx.x, t = threadIdx.x;
  __shared__ float a[256];
  a[t] = cb[e * 256 + t];
  __syncthreads();
  if (t == 0) {
    float tot = 0.f;
    for (int h = 0; h < 2; ++h) {
      const float* p = a + h * 128;
      float r[8];
#pragma unroll
      for (int j = 0; j < 8; ++j) r[j] = __fmul_rn(p[j], p[j]);
      for (int i = 8; i < 128; i += 8)
#pragma unroll
        for (int j = 0; j < 8; ++j) r[j] = __fadd_rn(r[j], __fmul_rn(p[i + j], p[i + j]));
      float s = __fadd_rn(__fadd_rn(__fadd_rn(r[0], r[1]), __fadd_rn(r[2], r[3])),
                          __fadd_rn(__fadd_rn(r[4], r[5]), __fadd_rn(r[6], r[7])));
      tot = (h == 0) ? s : __fadd_rn(tot, s);
    }
    c2f[e] = tot;
  }
}

// ---------------------------------------------------------------- VQ: 4 rows/block (R15, validated)
__global__ __launch_bounds__(256) void vq_ref_k(const float* __restrict__ z,
                                                const float* __restrict__ cb,
                                                const float* __restrict__ c2f,
                                                float* __restrict__ zq_out,
                                                float* __restrict__ idx_out) {
  int n0 = blockIdx.x * 4;
  int t = threadIdx.x;
  __shared__ float f[4][256];
  __shared__ float dist[4][1024];
  __shared__ float rr[4][2][8];
  __shared__ float f2s[4];
  __shared__ int bestIdx[4];
  for (int e = t; e < 1024; e += 256) {
    int r = e >> 8, c = e & 255;
    f[r][c] = z[(size_t)(n0 + r) * 256 + c];
  }
  __syncthreads();
  if (t < 64) {
    int row = t >> 4, hh = (t >> 3) & 1, j = t & 7;
    const float* p = f[row] + hh * 128;
    float r = __fmul_rn(p[j], p[j]);
    for (int i = 8; i < 128; i += 8) r = __fadd_rn(r, __fmul_rn(p[i + j], p[i + j]));
    rr[row][hh][j] = r;
  }
  __syncthreads();
  if (t < 4) {
    float s0 = __fadd_rn(__fadd_rn(__fadd_rn(rr[t][0][0], rr[t][0][1]), __fadd_rn(rr[t][0][2], rr[t][0][3])),
                         __fadd_rn(__fadd_rn(rr[t][0][4], rr[t][0][5]), __fadd_rn(rr[t][0][6], rr[t][0][7])));
    float s1 = __fadd_rn(__fadd_rn(__fadd_rn(rr[t][1][0], rr[t][1][1]), __fadd_rn(rr[t][1][2], rr[t][1][3])),
                         __fadd_rn(__fadd_rn(rr[t][1][4], rr[t][1][5]), __fadd_rn(rr[t][1][6], rr[t][1][7])));
    f2s[t] = __fadd_rn(s0, s1);
  }
  __syncthreads();
  for (int e = t; e < 1024; e += 256) {
    const float4* cbe = reinterpret_cast<const float4*>(cb + (size_t)e * 256);
    double d0 = 0.0, d1 = 0.0, d2 = 0.0, d3 = 0.0;
    for (int d = 0; d < 64; ++d) {
      float4 c4 = cbe[d];
      float4 f0 = *reinterpret_cast<const float4*>(&f[0][d * 4]);
      float4 f1 = *reinterpret_cast<const float4*>(&f[1][d * 4]);
      float4 f2v = *reinterpret_cast<const float4*>(&f[2][d * 4]);
      float4 f3 = *reinterpret_cast<const float4*>(&f[3][d * 4]);
      d0 = fma((double)f0.x, (double)c4.x, d0); d0 = fma((double)f0.y, (double)c4.y, d0);
      d0 = fma((double)f0.z, (double)c4.z, d0); d0 = fma((double)f0.w, (double)c4.w, d0);
      d1 = fma((double)f1.x, (double)c4.x, d1); d1 = fma((double)f1.y, (double)c4.y, d1);
      d1 = fma((double)f1.z, (double)c4.z, d1); d1 = fma((double)f1.w, (double)c4.w, d1);
      d2 = fma((double)f2v.x, (double)c4.x, d2); d2 = fma((double)f2v.y, (double)c4.y, d2);
      d2 = fma((double)f2v.z, (double)c4.z, d2); d2 = fma((double)f2v.w, (double)c4.w, d2);
      d3 = fma((double)f3.x, (double)c4.x, d3); d3 = fma((double)f3.y, (double)c4.y, d3);
      d3 = fma((double)f3.z, (double)c4.z, d3); d3 = fma((double)f3.w, (double)c4.w, d3);
    }
    float c2e = c2f[e];
    dist[0][e] = __fsub_rn(__fadd_rn(f2s[0], c2e), __fmul_rn(2.f, (float)d0));
    dist[1][e] = __fsub_rn(__fadd_rn(f2s[1], c2e), __fmul_rn(2.f, (float)d1));
    dist[2][e] = __fsub_rn(__fadd_rn(f2s[2], c2e), __fmul_rn(2.f, (float)d2));
    dist[3][e] = __fsub_rn(__fadd_rn(f2s[3], c2e), __fmul_rn(2.f, (float)d3));
  }
  __syncthreads();
  {
    int row = t >> 6, l = t & 63;
    float bv = dist[row][l];
    int bi = l;
    for (int e = l + 64; e < 1024; e += 64) {
      float v = dist[row][e];
      if (v < bv) { bv = v; bi = e; }
    }
#pragma unroll
    for (int m = 1; m < 64; m <<= 1) {
      float ov = __shfl_xor(bv, m, 64);
      int oi = __shfl_xor(bi, m, 64);
      if (ov < bv || (ov == bv && oi < bi)) { bv = ov; bi = oi; }
    }
    if (l == 0) {
      bestIdx[row] = bi;
      idx_out[n0 + row] = (float)bi;
    }
  }
  __syncthreads();
#pragma unroll
  for (int r = 0; r < 4; ++r)
    zq_out[(size_t)(n0 + r) * 256 + t] = cb[(size_t)bestIdx[r] * 256 + t];
}

// ================================================================ host
extern "C" void kernel_launch(void* const* d_in, const int* in_sizes, int n_in,
                              void* d_out, int out_size, void* d_ws, size_t ws_size,
                              hipStream_t stream) {
  const float* x = (const float*)d_in[0];
  const float* w0 = (const float*)d_in[1];
  const float* b0 = (const float*)d_in[2];
  const float* a_c1w = (const float*)d_in[3];
  const float* a_c1b = (const float*)d_in[4];
  const float* a_c2w = (const float*)d_in[5];
  const float* a_c2b = (const float*)d_in[6];
  const float* a_scw = (const float*)d_in[7];
  const float* a_scb = (const float*)d_in[8];
  const float* b_c1w = (const float*)d_in[9];
  const float* b_c1b = (const float*)d_in[10];
  const float* b_c2w = (const float*)d_in[11];
  const float* b_c2b = (const float*)d_in[12];
  const float* b_scw = (const float*)d_in[13];
  const float* b_scb = (const float*)d_in[14];
  const float* ew = (const float*)d_in[15];
  const float* eb = (const float*)d_in[16];
  const float* cb = (const float*)d_in[17];
  const float* d0w = (const float*)d_in[18];
  const float* d0b = (const float*)d_in[19];
  const float* dt1w = (const float*)d_in[20];
  const float* dt1b = (const float*)d_in[21];
  const float* dt2w = (const float*)d_in[22];
  const float* dt2b = (const float*)d_in[23];
  const float* doww = (const float*)d_in[24];
  const float* dob = (const float*)d_in[25];

  // ws (floats): A 13.1M | B 6.55M | C 6.55M | c2f 1k (layout = R21-proven)
  float* ws = (float*)d_ws;
  float* A = ws;
  float* Bf = ws + 13107200;
  float* Cf = ws + 19660800;
  float* c2f = ws + 26214400;
  _Float16* wh_ac1 = (_Float16*)(void*)Cf;
  _Float16* wh_bc1 = (_Float16*)(void*)(Bf + 3300000);
  _Float16* wh_ac2 = (_Float16*)(void*)(A + 6600000);
  _Float16* wh_bc2 = (_Float16*)(void*)(A + 3300000);
  _Float16* wh_d0  = (_Float16*)(void*)(A + 10000000);   // read before dt2 writes A
  __hip_bfloat16* wb_dt1 = (__hip_bfloat16*)(void*)A;
  __hip_bfloat16* wb_dt2 = (__hip_bfloat16*)(void*)(Bf + 3400000);

  float* outf = (float*)d_out;
  float* recon = outf;
  float* zq = outf + 409600;
  float* idxo = zq + 6553600;

  cbprep_np<<<1024, 256, 0, stream>>>(cb, c2f);

  for (int b = 0; b < 4; ++b) {
    const float* xb = x + (size_t)b * 102400;
    float* zqb = zq + (size_t)b * 1638400;
    float* idxb = idxo + (size_t)b * 6400;
    float* reconb = recon + (size_t)b * 102400;

    // encoder (z chain bit-identical to R21)
    conv0_k<<<320, 320, 0, stream>>>(xb, w0, b0, A);                   // A = h0
    prep_w3h_k<<<2304, 256, 0, stream>>>(a_c1w, wh_ac1, 128, 256);
    conv3s2_mfma_k<2><<<dim3(10, 160, 2), 256, 0, stream>>>(
        A, wh_ac1, a_c1b, Bf, 128, 320, 320, 256, 160, 160);           // Bf = a_c1
    conv1x1_k<2, false><<<dim3(400, 4), 256, 0, stream>>>(
        A, a_scw, a_scb, Cf, 128, 320, 320, 256, 160, 160);            // Cf = a_sc (fp32)
    prep_w3h_k<<<4608, 256, 0, stream>>>(a_c2w, wh_ac2, 256, 256);
    conv3s1_mfma_k<2><<<dim3(10, 160, 2), 256, 0, stream>>>(
        Bf, wh_ac2, a_c2b, Cf, A, 256, 160, 256);                      // A = a_out
    prep_w3h_k<<<9216, 256, 0, stream>>>(b_c1w, wh_bc1, 256, 512);
    conv3s2_mfma_k<2><<<dim3(5, 80, 4), 256, 0, stream>>>(
        A, wh_bc1, b_c1b, Bf, 256, 160, 160, 512, 80, 80);             // Bf = b_c1
    conv1x1_k<2, false><<<dim3(100, 8), 256, 0, stream>>>(
        A, b_scw, b_scb, Cf, 256, 160, 160, 512, 80, 80);              // Cf = b_sc (fp32)
    prep_w3h_k<<<18432, 256, 0, stream>>>(b_c2w, wh_bc2, 512, 512);
    conv3s1_mfma_k<2><<<dim3(5, 80, 4), 256, 0, stream>>>(
        Bf, wh_bc2, b_c2b, Cf, A, 512, 80, 512);                       // A = b_out
    conv1x1_k<1, false><<<dim3(100, 4), 256, 0, stream>>>(
        A, ew, eb, Cf, 512, 80, 80, 256, 80, 80);                      // Cf = z (fp32)
    // VQ
    vq_ref_k<<<1600, 256, 0, stream>>>(Cf, cb, c2f, zqb, idxb);
    // decoder (d0 on MFMA — cannot affect idx)
    prep_w1h_k<<<1024, 256, 0, stream>>>(d0w, wh_d0, 256, 512);
    conv1x1_mfma_k<1, true, 2><<<dim3(100, 16), 256, 0, stream>>>(
        zqb, wh_d0, d0b, Bf, 256, 80, 80, 512, 80, 80);                // Bf = g0
    prep_wb_k<<<8192, 256, 0, stream>>>(dt1w, wb_dt1, 512, 256);
    convt_mfma_k<<<dim3(5, 160, 4), 256, 0, stream>>>(
        Bf, wb_dt1, dt1b, Cf, 512, 80, 80, 256, 160, 160);             // Cf = g1
    prep_wb_k<<<2048, 256, 0, stream>>>(dt2w, wb_dt2, 256, 128);
    convt_mfma_k<<<dim3(10, 320, 2), 256, 0, stream>>>(
        Cf, wb_dt2, dt2b, A, 256, 160, 160, 128, 320, 320);            // A = g2
    dow_k<<<320, 320, 0, stream>>>(A, doww, dob, reconb);
  }
}

// Round 25
// 6235.040 us; speedup vs baseline: 1.3290x; 1.0399x over previous
//
#include <hip/hip_runtime.h>
#include <hip/hip_bf16.h>
#include <math.h>

// Round 25 (on R24, 6.48 ms): conv3s1 OYT=2 row-tiling — 2 output rows/block,
// 4 staged rows (fetch x0.67), A-frags shared across rows (A-traffic x0.5).
// Per-output MFMA sequence unchanged -> z bit-exact. Everything else R24.
// Diagnostic: absmax == 3.814697e-06.

static constexpr float kBNF = 0.9999950000374997f;

typedef short short8 __attribute__((ext_vector_type(8)));
typedef _Float16 half8 __attribute__((ext_vector_type(8)));
typedef float f32x4 __attribute__((ext_vector_type(4)));

// ---------------------------------------------------------------- conv0: 1->128, 3x3, s1, relu (B=1), fp32
__global__ __launch_bounds__(320) void conv0_k(const float* __restrict__ x,
                                               const float* __restrict__ w,
                                               const float* __restrict__ b,
                                               float* __restrict__ out) {
  const int H = 320, W = 320, OC = 128;
  int oy = blockIdx.x;
  int tx = threadIdx.x;
  __shared__ float in_s[3][W + 2];
  __shared__ float w_s[128 * 9];
  __shared__ float b_s[128];
  for (int e = tx; e < 3 * (W + 2); e += 320) {
    int r = e / (W + 2), c = e % (W + 2);
    int iy = oy + r - 1, ix = c - 1;
    float v = 0.f;
    if (iy >= 0 && iy < H && ix >= 0 && ix < W) v = x[iy * W + ix];
    in_s[r][c] = v;
  }
  for (int e = tx; e < 128 * 9; e += 320) w_s[e] = w[e];
  for (int e = tx; e < 128; e += 320) b_s[e] = b[e];
  __syncthreads();
  float iv[9];
#pragma unroll
  for (int r = 0; r < 3; ++r)
#pragma unroll
    for (int c = 0; c < 3; ++c) iv[r * 3 + c] = in_s[r][tx + c];
  for (int oc = 0; oc < OC; ++oc) {
    float acc = 0.f;
#pragma unroll
    for (int t = 0; t < 9; ++t) acc = fmaf(w_s[oc * 9 + t], iv[t], acc);
    float v32 = __fadd_rn(acc, b_s[oc]);
    v32 = __fmul_rn(v32, kBNF);
    out[(oc * H + oy) * W + tx] = fmaxf(v32, 0.f);
  }
}

// ---------------------------------------------------------------- conv3x3 weight prep -> fp16-split A-frags
__global__ __launch_bounds__(256) void prep_w3h_k(const float* __restrict__ w,
                                                  _Float16* __restrict__ wh,
                                                  int IC, int OC) {
  int i = blockIdx.x * 256 + threadIdx.x;
  int total = 2 * 9 * IC * OC;
  if (i >= total) return;
  int e = i & 7;
  int lane = (i >> 3) & 63;
  int rest = i >> 9;
  int ktiles = IC >> 5;
  int kT = rest % ktiles;
  int rest2 = rest / ktiles;
  int OCt = OC >> 4;
  int ocT = rest2 % OCt;
  int rest3 = rest2 / OCt;
  int tap = rest3 % 9;
  int split = rest3 / 9;
  int m = lane & 15, k = ((lane >> 4) << 3) + e;
  int oc = ocT * 16 + m, ic = kT * 32 + k;
  float v = w[((size_t)oc * IC + ic) * 9 + tap];
  _Float16 hi = (_Float16)v;
  wh[i] = (split == 0) ? hi : (_Float16)(v - (float)hi);
}

// ---------------------------------------------------------------- 1x1 conv weight prep -> fp16-split A-frags (d0)
__global__ __launch_bounds__(256) void prep_w1h_k(const float* __restrict__ w,
                                                  _Float16* __restrict__ wh,
                                                  int IC, int OC) {
  int i = blockIdx.x * 256 + threadIdx.x;
  int total = 2 * IC * OC;
  if (i >= total) return;
  int e = i & 7;
  int lane = (i >> 3) & 63;
  int rest = i >> 9;
  int ktiles = IC >> 5;
  int kT = rest % ktiles;
  int rest2 = rest / ktiles;
  int OCt = OC >> 4;
  int ocT = rest2 % OCt;
  int split = rest2 / OCt;
  int m = lane & 15, k = ((lane >> 4) << 3) + e;
  int oc = ocT * 16 + m, ic = kT * 32 + k;
  float v = w[(size_t)oc * IC + ic];
  _Float16 hi = (_Float16)v;
  wh[i] = (split == 0) ? hi : (_Float16)(v - (float)hi);
}

// ---------------------------------------------------------------- 1x1 conv via MFMA fp16-split (d0 only)
template <int S, bool RELU, int NOC>
__global__ __launch_bounds__(256) void conv1x1_mfma_k(
    const float* __restrict__ in, const _Float16* __restrict__ wh,
    const float* __restrict__ bias, float* __restrict__ out,
    int IC, int IH, int IW, int OC, int OH, int OW) {
  __shared__ __align__(16) _Float16 ldsH[64 * 40];
  __shared__ __align__(16) _Float16 ldsL[64 * 40];
  int t = threadIdx.x;
  int wv = t >> 6, l = t & 63;
  int px0 = blockIdx.x * 64;
  int ocT0 = blockIdx.y * NOC;
  const int P = OH * OW;
  const int ktiles = IC >> 5;
  const int OCt = OC >> 4;
  int n = l & 15, koff = (l >> 4) * 8;
  f32x4 acc[NOC];
#pragma unroll
  for (int j = 0; j < NOC; ++j) acc[j] = {0.f, 0.f, 0.f, 0.f};
  const half8* wh8 = reinterpret_cast<const half8*>(wh);
  for (int kT = 0; kT < ktiles; ++kT) {
    __syncthreads();
    for (int e = t; e < 2048; e += 256) {
      int pr = e & 63, ic = e >> 6;
      int p = px0 + pr;
      float v;
      if (S == 1) {
        v = in[(size_t)(kT * 32 + ic) * P + p];
      } else {
        int oy = p / OW, ox = p % OW;
        v = in[((size_t)(kT * 32 + ic) * IH + oy * S) * IW + ox * S];
      }
      _Float16 hi = (_Float16)v;
      ldsH[pr * 40 + ic] = hi;
      ldsL[pr * 40 + ic] = (_Float16)(v - (float)hi);
    }
    __syncthreads();
    half8 BH = *reinterpret_cast<const half8*>(&ldsH[(wv * 16 + n) * 40 + koff]);
    half8 BL = *reinterpret_cast<const half8*>(&ldsL[(wv * 16 + n) * 40 + koff]);
#pragma unroll
    for (int j = 0; j < NOC; ++j) {
      half8 AH = wh8[((0 * OCt + (ocT0 + j)) * ktiles + kT) * 64 + l];
      half8 AL = wh8[((1 * OCt + (ocT0 + j)) * ktiles + kT) * 64 + l];
      acc[j] = __builtin_amdgcn_mfma_f32_16x16x32_f16(AH, BH, acc[j], 0, 0, 0);
      acc[j] = __builtin_amdgcn_mfma_f32_16x16x32_f16(AH, BL, acc[j], 0, 0, 0);
      acc[j] = __builtin_amdgcn_mfma_f32_16x16x32_f16(AL, BH, acc[j], 0, 0, 0);
    }
  }
  int p = px0 + wv * 16 + n;
#pragma unroll
  for (int j = 0; j < NOC; ++j) {
    int oc0 = (ocT0 + j) * 16 + ((l >> 4) << 2);
#pragma unroll
    for (int r = 0; r < 4; ++r) {
      int oc = oc0 + r;
      float bv = bias[oc];
      float v32 = __fadd_rn(acc[j][r], bv);
      v32 = __fmul_rn(v32, kBNF);
      if (RELU) v32 = fmaxf(v32, 0.f);
      out[(size_t)oc * P + p] = v32;
    }
  }
}

// ---------------------------------------------------------------- 1x1 conv fp32 (a_sc / b_sc / e; R21-proven)
template <int S, bool RELU>
__global__ __launch_bounds__(256) void conv1x1_k(
    const float* __restrict__ in, const float* __restrict__ w,
    const float* __restrict__ bias, float* __restrict__ out,
    int IC, int IH, int IW, int OC, int OH, int OW) {
  __shared__ float in_s[16][64];
  __shared__ float w_s[16][64];
  const int P = OH * OW;
  int t = threadIdx.x;
  int p0 = blockIdx.x * 64;
  int oc0 = blockIdx.y * 64;
  int oc4 = (t >> 4) * 4, px4 = (t & 15) * 4;
  float acc[4][4] = {};
  for (int ic0 = 0; ic0 < IC; ic0 += 16) {
    __syncthreads();
    {
      int e = t;
#pragma unroll
      for (int k = 0; k < 4; ++k, e += 256) {
        int icr = e >> 6, pxr = e & 63;
        int p = p0 + pxr;
        float v = 0.f;
        if (p < P) {
          int oy = p / OW, ox = p % OW;
          v = in[((ic0 + icr) * IH + oy * S) * IW + ox * S];
        }
        in_s[icr][pxr] = v;
      }
      e = t;
#pragma unroll
      for (int k = 0; k < 4; ++k, e += 256) {
        int icr = e >> 6, ocr = e & 63;
        w_s[icr][ocr] = w[(oc0 + ocr) * IC + ic0 + icr];
      }
    }
    __syncthreads();
#pragma unroll
    for (int icr = 0; icr < 16; ++icr) {
      float4 iv = *reinterpret_cast<const float4*>(&in_s[icr][px4]);
      float4 wv = *reinterpret_cast<const float4*>(&w_s[icr][oc4]);
      const float* ip = (const float*)&iv;
      const float* wp = (const float*)&wv;
#pragma unroll
      for (int o = 0; o < 4; ++o)
#pragma unroll
        for (int p = 0; p < 4; ++p)
          acc[o][p] = fmaf(wp[o], ip[p], acc[o][p]);
    }
  }
  int p = p0 + px4;
  if (p < P) {
    int oy = p / OW, ox = p % OW;
#pragma unroll
    for (int o = 0; o < 4; ++o) {
      int oc = oc0 + oc4 + o;
      float bv = bias[oc];
      float4 rv;
      float* rp = (float*)&rv;
#pragma unroll
      for (int pp = 0; pp < 4; ++pp) {
        float v32 = __fadd_rn(acc[o][pp], bv);
        v32 = __fmul_rn(v32, kBNF);
        if (RELU) v32 = fmaxf(v32, 0.f);
        rp[pp] = v32;
      }
      *reinterpret_cast<float4*>(&out[((size_t)oc * OH + oy) * OW + ox]) = rv;
    }
  }
}

// ---------------------------------------------------------------- 3x3 conv S=1 via MFMA fp16-split, OYT=2, NOC ocT/wave
// 2 output rows per block: stage rows oy0-1..oy0+2 (4 rows); A-frags shared
// across rows. Per-output MFMA order (kT asc, ky, kx, HBH/HBL/LBH) unchanged.
template <int NOC>
__global__ __launch_bounds__(256) void conv3s1_mfma_k(
    const float* __restrict__ in, const _Float16* __restrict__ wh,
    const float* __restrict__ bias, const float* __restrict__ skip,
    float* __restrict__ out, int IC, int HW_, int OC) {
  __shared__ __align__(16) _Float16 ldsH[4 * 20 * 40];
  __shared__ __align__(16) _Float16 ldsL[4 * 20 * 40];
  int t = threadIdx.x;
  int wv = t >> 6, l = t & 63;
  int px0 = blockIdx.x * 16;
  int oy0 = blockIdx.y * 2;
  int ocT0 = (blockIdx.z * 4 + wv) * NOC;
  const int ktiles = IC >> 5;
  const int OCt = OC >> 4;
  int n = l & 15, koff = (l >> 4) * 8;
  f32x4 acc[NOC][2];
#pragma unroll
  for (int j = 0; j < NOC; ++j)
#pragma unroll
    for (int r2 = 0; r2 < 2; ++r2) acc[j][r2] = {0.f, 0.f, 0.f, 0.f};
  const half8* wh8 = reinterpret_cast<const half8*>(wh);
  for (int kT = 0; kT < ktiles; ++kT) {
    __syncthreads();
    for (int e = t; e < 2304; e += 256) {  // 4 rows * 18 xi * 32 ic
      int xi = e % 18;
      int rem = e / 18;
      int ic = rem & 31, r = rem >> 5;
      int iy = oy0 - 1 + r;
      int ix = px0 - 1 + xi;
      float v = 0.f;
      if (iy >= 0 && iy < HW_ && ix >= 0 && ix < HW_)
        v = in[((size_t)(kT * 32 + ic) * HW_ + iy) * HW_ + ix];
      _Float16 hi = (_Float16)v;
      ldsH[(r * 20 + xi) * 40 + ic] = hi;
      ldsL[(r * 20 + xi) * 40 + ic] = (_Float16)(v - (float)hi);
    }
    __syncthreads();
#pragma unroll
    for (int ky = 0; ky < 3; ++ky) {
#pragma unroll
      for (int kx = 0; kx < 3; ++kx) {
        int tap = ky * 3 + kx;
        half8 BH0 = *reinterpret_cast<const half8*>(&ldsH[((0 + ky) * 20 + n + kx) * 40 + koff]);
        half8 BL0 = *reinterpret_cast<const half8*>(&ldsL[((0 + ky) * 20 + n + kx) * 40 + koff]);
        half8 BH1 = *reinterpret_cast<const half8*>(&ldsH[((1 + ky) * 20 + n + kx) * 40 + koff]);
        half8 BL1 = *reinterpret_cast<const half8*>(&ldsL[((1 + ky) * 20 + n + kx) * 40 + koff]);
#pragma unroll
        for (int j = 0; j < NOC; ++j) {
          half8 AH = wh8[(((tap)*OCt + (ocT0 + j)) * ktiles + kT) * 64 + l];
          half8 AL = wh8[(((9 + tap) * OCt + (ocT0 + j)) * ktiles + kT) * 64 + l];
          acc[j][0] = __builtin_amdgcn_mfma_f32_16x16x32_f16(AH, BH0, acc[j][0], 0, 0, 0);
          acc[j][0] = __builtin_amdgcn_mfma_f32_16x16x32_f16(AH, BL0, acc[j][0], 0, 0, 0);
          acc[j][0] = __builtin_amdgcn_mfma_f32_16x16x32_f16(AL, BH0, acc[j][0], 0, 0, 0);
          acc[j][1] = __builtin_amdgcn_mfma_f32_16x16x32_f16(AH, BH1, acc[j][1], 0, 0, 0);
          acc[j][1] = __builtin_amdgcn_mfma_f32_16x16x32_f16(AH, BL1, acc[j][1], 0, 0, 0);
          acc[j][1] = __builtin_amdgcn_mfma_f32_16x16x32_f16(AL, BH1, acc[j][1], 0, 0, 0);
        }
      }
    }
  }
  int ox = px0 + n;
#pragma unroll
  for (int j = 0; j < NOC; ++j) {
    int oc0 = (ocT0 + j) * 16 + ((l >> 4) << 2);
#pragma unroll
    for (int r2 = 0; r2 < 2; ++r2) {
      int oy = oy0 + r2;
#pragma unroll
      for (int r = 0; r < 4; ++r) {
        int oc = oc0 + r;
        float bv = bias[oc];
        size_t idx = ((size_t)oc * HW_ + oy) * HW_ + ox;
        float v32 = __fadd_rn(acc[j][r2][r], bv);
        v32 = __fmul_rn(v32, kBNF);
        v32 = __fadd_rn(v32, skip[idx]);
        out[idx] = fmaxf(v32, 0.f);
      }
    }
  }
}

// ---------------------------------------------------------------- 3x3 conv S=2 via MFMA fp16-split, parity LDS, NOC
template <int NOC>
__global__ __launch_bounds__(256) void conv3s2_mfma_k(
    const float* __restrict__ in, const _Float16* __restrict__ wh,
    const float* __restrict__ bias, float* __restrict__ out,
    int IC, int IH, int IW, int OC, int OH, int OW) {
  __shared__ __align__(16) _Float16 ldsEH[3 * 17 * 40];
  __shared__ __align__(16) _Float16 ldsEL[3 * 17 * 40];
  __shared__ __align__(16) _Float16 ldsOH[3 * 16 * 40];
  __shared__ __align__(16) _Float16 ldsOL[3 * 16 * 40];
  int t = threadIdx.x;
  int wv = t >> 6, l = t & 63;
  int px0 = blockIdx.x * 16;
  int oy = blockIdx.y;
  int ocT0 = (blockIdx.z * 4 + wv) * NOC;
  const int ktiles = IC >> 5;
  const int OCt = OC >> 4;
  int n = l & 15, koff = (l >> 4) * 8;
  f32x4 acc[NOC];
#pragma unroll
  for (int j = 0; j < NOC; ++j) acc[j] = {0.f, 0.f, 0.f, 0.f};
  const half8* wh8 = reinterpret_cast<const half8*>(wh);
  for (int kT = 0; kT < ktiles; ++kT) {
    __syncthreads();
    for (int e = t; e < 3168; e += 256) {
      int ic = e & 31;
      int rem = e >> 5;
      int xi = rem % 33, ky = rem / 33;
      int iy = oy * 2 - 1 + ky;
      int ix = px0 * 2 - 1 + xi;
      float v = 0.f;
      if (iy >= 0 && iy < IH && ix >= 0 && ix < IW)
        v = in[((size_t)(kT * 32 + ic) * IH + iy) * IW + ix];
      _Float16 hi = (_Float16)v;
      _Float16 lo = (_Float16)(v - (float)hi);
      int hrow = xi >> 1;
      if (xi & 1) {
        ldsOH[(ky * 16 + hrow) * 40 + ic] = hi;
        ldsOL[(ky * 16 + hrow) * 40 + ic] = lo;
      } else {
        ldsEH[(ky * 17 + hrow) * 40 + ic] = hi;
        ldsEL[(ky * 17 + hrow) * 40 + ic] = lo;
      }
    }
    __syncthreads();
#pragma unroll
    for (int ky = 0; ky < 3; ++ky) {
#pragma unroll
      for (int kx = 0; kx < 3; ++kx) {
        int tap = ky * 3 + kx;
        half8 BH, BL;
        if (kx == 0) {
          BH = *reinterpret_cast<const half8*>(&ldsEH[(ky * 17 + n) * 40 + koff]);
          BL = *reinterpret_cast<const half8*>(&ldsEL[(ky * 17 + n) * 40 + koff]);
        } else if (kx == 1) {
          BH = *reinterpret_cast<const half8*>(&ldsOH[(ky * 16 + n) * 40 + koff]);
          BL = *reinterpret_cast<const half8*>(&ldsOL[(ky * 16 + n) * 40 + koff]);
        } else {
          BH = *reinterpret_cast<const half8*>(&ldsEH[(ky * 17 + n + 1) * 40 + koff]);
          BL = *reinterpret_cast<const half8*>(&ldsEL[(ky * 17 + n + 1) * 40 + koff]);
        }
#pragma unroll
        for (int j = 0; j < NOC; ++j) {
          half8 AH = wh8[(((tap)*OCt + (ocT0 + j)) * ktiles + kT) * 64 + l];
          half8 AL = wh8[(((9 + tap) * OCt + (ocT0 + j)) * ktiles + kT) * 64 + l];
          acc[j] = __builtin_amdgcn_mfma_f32_16x16x32_f16(AH, BH, acc[j], 0, 0, 0);
          acc[j] = __builtin_amdgcn_mfma_f32_16x16x32_f16(AH, BL, acc[j], 0, 0, 0);
          acc[j] = __builtin_amdgcn_mfma_f32_16x16x32_f16(AL, BH, acc[j], 0, 0, 0);
        }
      }
    }
  }
  int ox = px0 + n;
#pragma unroll
  for (int j = 0; j < NOC; ++j) {
    int oc0 = (ocT0 + j) * 16 + ((l >> 4) << 2);
#pragma unroll
    for (int r = 0; r < 4; ++r) {
      int oc = oc0 + r;
      float bv = bias[oc];
      size_t idx = ((size_t)oc * OH + oy) * OW + ox;
      float v32 = __fadd_rn(acc[j][r], bv);
      v32 = __fmul_rn(v32, kBNF);
      out[idx] = fmaxf(v32, 0.f);
    }
  }
}

// ---------------------------------------------------------------- ConvT weight prep -> bf16 A-fragments (R14)
__global__ __launch_bounds__(256) void prep_wb_k(const float* __restrict__ w,
                                                 __hip_bfloat16* __restrict__ wb,
                                                 int IC, int OC) {
  int i = blockIdx.x * 256 + threadIdx.x;
  int total = 16 * IC * OC;
  if (i >= total) return;
  int per_cfg = IC * OC;
  int cfg = i / per_cfg;
  int r = i - cfg * per_cfg;
  int ktiles = IC >> 5;
  int ocT = r / (ktiles * 512);
  int r2 = r - ocT * (ktiles * 512);
  int kT = r2 >> 9;
  int f = r2 & 511;
  int lane = f >> 3, e = f & 7;
  int m = lane & 15, kk = ((lane >> 4) << 3) + e;
  int oc = ocT * 16 + m, ic = kT * 32 + kk;
  int kyb = cfg >> 3, ty = (cfg >> 2) & 1, kx = cfg & 3;
  int ky = kyb + 2 * ty;
  wb[i] = __float2bfloat16(w[((size_t)ic * OC + oc) * 16 + ky * 4 + kx]);
}

// ---------------------------------------------------------------- ConvT k4 s2 p1 via MFMA bf16 (R14, validated)
__global__ __launch_bounds__(256) void convt_mfma_k(
    const float* __restrict__ in, const __hip_bfloat16* __restrict__ wb,
    const float* __restrict__ bias, float* __restrict__ out,
    int IC, int IH, int IW, int OC, int OH, int OW) {
  __shared__ __align__(16) __hip_bfloat16 lds[2 * 18 * 40];
  int t = threadIdx.x;
  int wv = t >> 6, l = t & 63;
  int ox0 = blockIdx.x * 32;
  int oy = blockIdx.y;
  int oc0w = blockIdx.z * 64 + wv * 16;
  int kyb = (oy & 1) ? 0 : 1;
  int hb = ox0 >> 1;
  int iy0n = oy + 1 - kyb;
  int iy0 = iy0n >> 1;
  bool ok0 = (iy0 < IH);
  int iy1n = oy + 1 - kyb - 2;
  int iy1 = iy1n >> 1;
  bool ok1 = (iy1n >= 0) && (iy1 < IH);
  f32x4 accE = {0.f, 0.f, 0.f, 0.f};
  f32x4 accO = {0.f, 0.f, 0.f, 0.f};
  const int ktiles = IC >> 5;
  int n = l & 15, koff = (l >> 4) * 8;
  const short8* wb8 = reinterpret_cast<const short8*>(wb);
  int ocT = oc0w >> 4;
  const int OCt = OC >> 4;
  for (int kT = 0; kT < ktiles; ++kT) {
    __syncthreads();
    for (int e = t; e < 1152; e += 256) {
      int ic = e / 36;
      int r = e - ic * 36;
      int ty = r / 18, xi = r - ty * 18;
      int ix = hb - 1 + xi;
      int iy = ty ? iy1 : iy0;
      bool ok = ty ? ok1 : ok0;
      float v = 0.f;
      if (ok && ix >= 0 && ix < IW)
        v = in[((size_t)(kT * 32 + ic) * IH + iy) * IW + ix];
      lds[(ty * 18 + xi) * 40 + ic] = __float2bfloat16(v);
    }
    __syncthreads();
#pragma unroll
    for (int ty = 0; ty < 2; ++ty) {
      short8 A0 = wb8[((((kyb * 2 + ty) * 4 + 0) * OCt + ocT) * ktiles + kT) * 64 + l];
      short8 A1 = wb8[((((kyb * 2 + ty) * 4 + 1) * OCt + ocT) * ktiles + kT) * 64 + l];
      short8 A2 = wb8[((((kyb * 2 + ty) * 4 + 2) * OCt + ocT) * ktiles + kT) * 64 + l];
      short8 A3 = wb8[((((kyb * 2 + ty) * 4 + 3) * OCt + ocT) * ktiles + kT) * 64 + l];
      short8 b0 = *reinterpret_cast<const short8*>(&lds[(ty * 18 + 0 + n) * 40 + koff]);
      short8 b1 = *reinterpret_cast<const short8*>(&lds[(ty * 18 + 1 + n) * 40 + koff]);
      short8 b2 = *reinterpret_cast<const short8*>(&lds[(ty * 18 + 2 + n) * 40 + koff]);
      accE = __builtin_amdgcn_mfma_f32_16x16x32_bf16(A1, b1, accE, 0, 0, 0);
      accE = __builtin_amdgcn_mfma_f32_16x16x32_bf16(A3, b0, accE, 0, 0, 0);
      accO = __builtin_amdgcn_mfma_f32_16x16x32_bf16(A0, b2, accO, 0, 0, 0);
      accO = __builtin_amdgcn_mfma_f32_16x16x32_bf16(A2, b1, accO, 0, 0, 0);
    }
  }
  int ocr0 = oc0w + ((l >> 4) << 2);
  int oxE = ox0 + 2 * n;
  int oxO = ox0 + 1 + 2 * n;
#pragma unroll
  for (int r = 0; r < 4; ++r) {
    float bv = bias[ocr0 + r];
    size_t rowbase = ((size_t)(ocr0 + r) * OH + oy) * OW;
    out[rowbase + oxE] = fmaxf((accE[r] + bv) * kBNF, 0.f);
    out[rowbase + oxO] = fmaxf((accO[r] + bv) * kBNF, 0.f);
  }
}

// ---------------------------------------------------------------- final 3x3 conv 128->1 + sigmoid (R9)
__global__ __launch_bounds__(320) void dow_k(const float* __restrict__ in,
                                             const float* __restrict__ w,
                                             const float* __restrict__ bias,
                                             float* __restrict__ out) {
  const int H = 320, W = 320, IC = 128;
  int oy = blockIdx.x;
  int tx = threadIdx.x;
  __shared__ float in_s[4][3][W + 2];
  __shared__ float w_s[IC * 9];
  for (int e = tx; e < IC * 9; e += 320) w_s[e] = w[e];
  float acc = 0.f;
  for (int ic0 = 0; ic0 < IC; ic0 += 4) {
    __syncthreads();
    for (int e = tx; e < 4 * 3 * (W + 2); e += 320) {
      int icr = e / (3 * (W + 2));
      int rem = e - icr * (3 * (W + 2));
      int r = rem / (W + 2), c = rem - r * (W + 2);
      int iy = oy + r - 1, ix = c - 1;
      float v = 0.f;
      if (iy >= 0 && iy < H && ix >= 0 && ix < W)
        v = in[((ic0 + icr) * H + iy) * W + ix];
      in_s[icr][r][c] = v;
    }
    __syncthreads();
#pragma unroll
    for (int icr = 0; icr < 4; ++icr)
#pragma unroll
      for (int r = 0; r < 3; ++r)
#pragma unroll
        for (int c = 0; c < 3; ++c)
          acc = fmaf(w_s[(ic0 + icr) * 9 + r * 3 + c], in_s[icr][r][tx + c], acc);
  }
  acc += bias[0];
  out[oy * W + tx] = 1.f / (1.f + expf(-acc));
}

// ---------------------------------------------------------------- codebook sq-norms: numpy-pairwise fp32
__global__ __launch_bounds__(256) void cbprep_np(const float* __restrict__ cb,
                                                 float* __restrict__ c2f) {
  int e = blockIdx.x, t = threadIdx.x;
  __shared__ float a[256];
  a[t] = cb[e * 256 + t];
  __syncthreads();
  if (t == 0) {
    float tot = 0.f;
    for (int h = 0; h < 2; ++h) {
      const float* p = a + h * 128;
      float r[8];
#pragma unroll
      for (int j = 0; j < 8; ++j) r[j] = __fmul_rn(p[j], p[j]);
      for (int i = 8; i < 128; i += 8)
#pragma unroll
        for (int j = 0; j < 8; ++j) r[j] = __fadd_rn(r[j], __fmul_rn(p[i + j], p[i + j]));
      float s = __fadd_rn(__fadd_rn(__fadd_rn(r[0], r[1]), __fadd_rn(r[2], r[3])),
                          __fadd_rn(__fadd_rn(r[4], r[5]), __fadd_rn(r[6], r[7])));
      tot = (h == 0) ? s : __fadd_rn(tot, s);
    }
    c2f[e] = tot;
  }
}

// ---------------------------------------------------------------- VQ: 4 rows/block (R15, validated)
__global__ __launch_bounds__(256) void vq_ref_k(const float* __restrict__ z,
                                                const float* __restrict__ cb,
                                                const float* __restrict__ c2f,
                                                float* __restrict__ zq_out,
                                                float* __restrict__ idx_out) {
  int n0 = blockIdx.x * 4;
  int t = threadIdx.x;
  __shared__ float f[4][256];
  __shared__ float dist[4][1024];
  __shared__ float rr[4][2][8];
  __shared__ float f2s[4];
  __shared__ int bestIdx[4];
  for (int e = t; e < 1024; e += 256) {
    int r = e >> 8, c = e & 255;
    f[r][c] = z[(size_t)(n0 + r) * 256 + c];
  }
  __syncthreads();
  if (t < 64) {
    int row = t >> 4, hh = (t >> 3) & 1, j = t & 7;
    const float* p = f[row] + hh * 128;
    float r = __fmul_rn(p[j], p[j]);
    for (int i = 8; i < 128; i += 8) r = __fadd_rn(r, __fmul_rn(p[i + j], p[i + j]));
    rr[row][hh][j] = r;
  }
  __syncthreads();
  if (t < 4) {
    float s0 = __fadd_rn(__fadd_rn(__fadd_rn(rr[t][0][0], rr[t][0][1]), __fadd_rn(rr[t][0][2], rr[t][0][3])),
                         __fadd_rn(__fadd_rn(rr[t][0][4], rr[t][0][5]), __fadd_rn(rr[t][0][6], rr[t][0][7])));
    float s1 = __fadd_rn(__fadd_rn(__fadd_rn(rr[t][1][0], rr[t][1][1]), __fadd_rn(rr[t][1][2], rr[t][1][3])),
                         __fadd_rn(__fadd_rn(rr[t][1][4], rr[t][1][5]), __fadd_rn(rr[t][1][6], rr[t][1][7])));
    f2s[t] = __fadd_rn(s0, s1);
  }
  __syncthreads();
  for (int e = t; e < 1024; e += 256) {
    const float4* cbe = reinterpret_cast<const float4*>(cb + (size_t)e * 256);
    double d0 = 0.0, d1 = 0.0, d2 = 0.0, d3 = 0.0;
    for (int d = 0; d < 64; ++d) {
      float4 c4 = cbe[d];
      float4 f0 = *reinterpret_cast<const float4*>(&f[0][d * 4]);
      float4 f1 = *reinterpret_cast<const float4*>(&f[1][d * 4]);
      float4 f2v = *reinterpret_cast<const float4*>(&f[2][d * 4]);
      float4 f3 = *reinterpret_cast<const float4*>(&f[3][d * 4]);
      d0 = fma((double)f0.x, (double)c4.x, d0); d0 = fma((double)f0.y, (double)c4.y, d0);
      d0 = fma((double)f0.z, (double)c4.z, d0); d0 = fma((double)f0.w, (double)c4.w, d0);
      d1 = fma((double)f1.x, (double)c4.x, d1); d1 = fma((double)f1.y, (double)c4.y, d1);
      d1 = fma((double)f1.z, (double)c4.z, d1); d1 = fma((double)f1.w, (double)c4.w, d1);
      d2 = fma((double)f2v.x, (double)c4.x, d2); d2 = fma((double)f2v.y, (double)c4.y, d2);
      d2 = fma((double)f2v.z, (double)c4.z, d2); d2 = fma((double)f2v.w, (double)c4.w, d2);
      d3 = fma((double)f3.x, (double)c4.x, d3); d3 = fma((double)f3.y, (double)c4.y, d3);
      d3 = fma((double)f3.z, (double)c4.z, d3); d3 = fma((double)f3.w, (double)c4.w, d3);
    }
    float c2e = c2f[e];
    dist[0][e] = __fsub_rn(__fadd_rn(f2s[0], c2e), __fmul_rn(2.f, (float)d0));
    dist[1][e] = __fsub_rn(__fadd_rn(f2s[1], c2e), __fmul_rn(2.f, (float)d1));
    dist[2][e] = __fsub_rn(__fadd_rn(f2s[2], c2e), __fmul_rn(2.f, (float)d2));
    dist[3][e] = __fsub_rn(__fadd_rn(f2s[3], c2e), __fmul_rn(2.f, (float)d3));
  }
  __syncthreads();
  {
    int row = t >> 6, l = t & 63;
    float bv = dist[row][l];
    int bi = l;
    for (int e = l + 64; e < 1024; e += 64) {
      float v = dist[row][e];
      if (v < bv) { bv = v; bi = e; }
    }
#pragma unroll
    for (int m = 1; m < 64; m <<= 1) {
      float ov = __shfl_xor(bv, m, 64);
      int oi = __shfl_xor(bi, m, 64);
      if (ov < bv || (ov == bv && oi < bi)) { bv = ov; bi = oi; }
    }
    if (l == 0) {
      bestIdx[row] = bi;
      idx_out[n0 + row] = (float)bi;
    }
  }
  __syncthreads();
#pragma unroll
  for (int r = 0; r < 4; ++r)
    zq_out[(size_t)(n0 + r) * 256 + t] = cb[(size_t)bestIdx[r] * 256 + t];
}

// ================================================================ host
extern "C" void kernel_launch(void* const* d_in, const int* in_sizes, int n_in,
                              void* d_out, int out_size, void* d_ws, size_t ws_size,
                              hipStream_t stream) {
  const float* x = (const float*)d_in[0];
  const float* w0 = (const float*)d_in[1];
  const float* b0 = (const float*)d_in[2];
  const float* a_c1w = (const float*)d_in[3];
  const float* a_c1b = (const float*)d_in[4];
  const float* a_c2w = (const float*)d_in[5];
  const float* a_c2b = (const float*)d_in[6];
  const float* a_scw = (const float*)d_in[7];
  const float* a_scb = (const float*)d_in[8];
  const float* b_c1w = (const float*)d_in[9];
  const float* b_c1b = (const float*)d_in[10];
  const float* b_c2w = (const float*)d_in[11];
  const float* b_c2b = (const float*)d_in[12];
  const float* b_scw = (const float*)d_in[13];
  const float* b_scb = (const float*)d_in[14];
  const float* ew = (const float*)d_in[15];
  const float* eb = (const float*)d_in[16];
  const float* cb = (const float*)d_in[17];
  const float* d0w = (const float*)d_in[18];
  const float* d0b = (const float*)d_in[19];
  const float* dt1w = (const float*)d_in[20];
  const float* dt1b = (const float*)d_in[21];
  const float* dt2w = (const float*)d_in[22];
  const float* dt2b = (const float*)d_in[23];
  const float* doww = (const float*)d_in[24];
  const float* dob = (const float*)d_in[25];

  // ws (floats): A 13.1M | B 6.55M | C 6.55M | c2f 1k (layout = R21-proven)
  float* ws = (float*)d_ws;
  float* A = ws;
  float* Bf = ws + 13107200;
  float* Cf = ws + 19660800;
  float* c2f = ws + 26214400;
  _Float16* wh_ac1 = (_Float16*)(void*)Cf;
  _Float16* wh_bc1 = (_Float16*)(void*)(Bf + 3300000);
  _Float16* wh_ac2 = (_Float16*)(void*)(A + 6600000);
  _Float16* wh_bc2 = (_Float16*)(void*)(A + 3300000);
  _Float16* wh_d0  = (_Float16*)(void*)(A + 10000000);
  __hip_bfloat16* wb_dt1 = (__hip_bfloat16*)(void*)A;
  __hip_bfloat16* wb_dt2 = (__hip_bfloat16*)(void*)(Bf + 3400000);

  float* outf = (float*)d_out;
  float* recon = outf;
  float* zq = outf + 409600;
  float* idxo = zq + 6553600;

  cbprep_np<<<1024, 256, 0, stream>>>(cb, c2f);

  for (int b = 0; b < 4; ++b) {
    const float* xb = x + (size_t)b * 102400;
    float* zqb = zq + (size_t)b * 1638400;
    float* idxb = idxo + (size_t)b * 6400;
    float* reconb = recon + (size_t)b * 102400;

    // encoder (z chain bit-identical)
    conv0_k<<<320, 320, 0, stream>>>(xb, w0, b0, A);                   // A = h0
    prep_w3h_k<<<2304, 256, 0, stream>>>(a_c1w, wh_ac1, 128, 256);
    conv3s2_mfma_k<2><<<dim3(10, 160, 2), 256, 0, stream>>>(
        A, wh_ac1, a_c1b, Bf, 128, 320, 320, 256, 160, 160);           // Bf = a_c1
    conv1x1_k<2, false><<<dim3(400, 4), 256, 0, stream>>>(
        A, a_scw, a_scb, Cf, 128, 320, 320, 256, 160, 160);            // Cf = a_sc (fp32)
    prep_w3h_k<<<4608, 256, 0, stream>>>(a_c2w, wh_ac2, 256, 256);
    conv3s1_mfma_k<2><<<dim3(10, 80, 2), 256, 0, stream>>>(
        Bf, wh_ac2, a_c2b, Cf, A, 256, 160, 256);                      // A = a_out (OYT=2)
    prep_w3h_k<<<9216, 256, 0, stream>>>(b_c1w, wh_bc1, 256, 512);
    conv3s2_mfma_k<2><<<dim3(5, 80, 4), 256, 0, stream>>>(
        A, wh_bc1, b_c1b, Bf, 256, 160, 160, 512, 80, 80);             // Bf = b_c1
    conv1x1_k<2, false><<<dim3(100, 8), 256, 0, stream>>>(
        A, b_scw, b_scb, Cf, 256, 160, 160, 512, 80, 80);              // Cf = b_sc (fp32)
    prep_w3h_k<<<18432, 256, 0, stream>>>(b_c2w, wh_bc2, 512, 512);
    conv3s1_mfma_k<2><<<dim3(5, 40, 4), 256, 0, stream>>>(
        Bf, wh_bc2, b_c2b, Cf, A, 512, 80, 512);                       // A = b_out (OYT=2)
    conv1x1_k<1, false><<<dim3(100, 4), 256, 0, stream>>>(
        A, ew, eb, Cf, 512, 80, 80, 256, 80, 80);                      // Cf = z (fp32)
    // VQ
    vq_ref_k<<<1600, 256, 0, stream>>>(Cf, cb, c2f, zqb, idxb);
    // decoder
    prep_w1h_k<<<1024, 256, 0, stream>>>(d0w, wh_d0, 256, 512);
    conv1x1_mfma_k<1, true, 2><<<dim3(100, 16), 256, 0, stream>>>(
        zqb, wh_d0, d0b, Bf, 256, 80, 80, 512, 80, 80);                // Bf = g0
    prep_wb_k<<<8192, 256, 0, stream>>>(dt1w, wb_dt1, 512, 256);
    convt_mfma_k<<<dim3(5, 160, 4), 256, 0, stream>>>(
        Bf, wb_dt1, dt1b, Cf, 512, 80, 80, 256, 160, 160);             // Cf = g1
    prep_wb_k<<<2048, 256, 0, stream>>>(dt2w, wb_dt2, 256, 128);
    convt_mfma_k<<<dim3(10, 320, 2), 256, 0, stream>>>(
        Cf, wb_dt2, dt2b, A, 256, 160, 160, 128, 320, 320);            // A = g2
    dow_k<<<320, 320, 0, stream>>>(A, doww, dob, reconb);
  }
}

// Round 26
// 6194.708 us; speedup vs baseline: 1.3377x; 1.0065x over previous
//
#include <hip/hip_runtime.h>
#include <hip/hip_bf16.h>
#include <math.h>

// Round 26 (on R25, 6.24 ms): three arithmetic-preserving occupancy fixes.
//  1. vq_ref_k 512 threads (2 entries/thread) — fp64 chains + first-index
//     reduction per-entry identical; more waves hide latency.
//  2. dow_k half-row split (R10-validated), 640 blocks.
//  3. conv0_k oc-split x2, 640 blocks.
// z chain bit-identical. Diagnostic: absmax == 3.814697e-06.

static constexpr float kBNF = 0.9999950000374997f;

typedef short short8 __attribute__((ext_vector_type(8)));
typedef _Float16 half8 __attribute__((ext_vector_type(8)));
typedef float f32x4 __attribute__((ext_vector_type(4)));

// ---------------------------------------------------------------- conv0: 1->128, 3x3, s1, relu (B=1), oc-split
__global__ __launch_bounds__(320) void conv0_k(const float* __restrict__ x,
                                               const float* __restrict__ w,
                                               const float* __restrict__ b,
                                               float* __restrict__ out) {
  const int H = 320, W = 320;
  int oy = blockIdx.x;
  int oc0 = blockIdx.y * 64;
  int tx = threadIdx.x;
  __shared__ float in_s[3][W + 2];
  __shared__ float w_s[64 * 9];
  __shared__ float b_s[64];
  for (int e = tx; e < 3 * (W + 2); e += 320) {
    int r = e / (W + 2), c = e % (W + 2);
    int iy = oy + r - 1, ix = c - 1;
    float v = 0.f;
    if (iy >= 0 && iy < H && ix >= 0 && ix < W) v = x[iy * W + ix];
    in_s[r][c] = v;
  }
  for (int e = tx; e < 64 * 9; e += 320) w_s[e] = w[oc0 * 9 + e];
  for (int e = tx; e < 64; e += 320) b_s[e] = b[oc0 + e];
  __syncthreads();
  float iv[9];
#pragma unroll
  for (int r = 0; r < 3; ++r)
#pragma unroll
    for (int c = 0; c < 3; ++c) iv[r * 3 + c] = in_s[r][tx + c];
  for (int o = 0; o < 64; ++o) {
    float acc = 0.f;
#pragma unroll
    for (int t = 0; t < 9; ++t) acc = fmaf(w_s[o * 9 + t], iv[t], acc);
    float v32 = __fadd_rn(acc, b_s[o]);
    v32 = __fmul_rn(v32, kBNF);
    out[((oc0 + o) * H + oy) * W + tx] = fmaxf(v32, 0.f);
  }
}

// ---------------------------------------------------------------- conv3x3 weight prep -> fp16-split A-frags
__global__ __launch_bounds__(256) void prep_w3h_k(const float* __restrict__ w,
                                                  _Float16* __restrict__ wh,
                                                  int IC, int OC) {
  int i = blockIdx.x * 256 + threadIdx.x;
  int total = 2 * 9 * IC * OC;
  if (i >= total) return;
  int e = i & 7;
  int lane = (i >> 3) & 63;
  int rest = i >> 9;
  int ktiles = IC >> 5;
  int kT = rest % ktiles;
  int rest2 = rest / ktiles;
  int OCt = OC >> 4;
  int ocT = rest2 % OCt;
  int rest3 = rest2 / OCt;
  int tap = rest3 % 9;
  int split = rest3 / 9;
  int m = lane & 15, k = ((lane >> 4) << 3) + e;
  int oc = ocT * 16 + m, ic = kT * 32 + k;
  float v = w[((size_t)oc * IC + ic) * 9 + tap];
  _Float16 hi = (_Float16)v;
  wh[i] = (split == 0) ? hi : (_Float16)(v - (float)hi);
}

// ---------------------------------------------------------------- 1x1 conv weight prep -> fp16-split A-frags (d0)
__global__ __launch_bounds__(256) void prep_w1h_k(const float* __restrict__ w,
                                                  _Float16* __restrict__ wh,
                                                  int IC, int OC) {
  int i = blockIdx.x * 256 + threadIdx.x;
  int total = 2 * IC * OC;
  if (i >= total) return;
  int e = i & 7;
  int lane = (i >> 3) & 63;
  int rest = i >> 9;
  int ktiles = IC >> 5;
  int kT = rest % ktiles;
  int rest2 = rest / ktiles;
  int OCt = OC >> 4;
  int ocT = rest2 % OCt;
  int split = rest2 / OCt;
  int m = lane & 15, k = ((lane >> 4) << 3) + e;
  int oc = ocT * 16 + m, ic = kT * 32 + k;
  float v = w[(size_t)oc * IC + ic];
  _Float16 hi = (_Float16)v;
  wh[i] = (split == 0) ? hi : (_Float16)(v - (float)hi);
}

// ---------------------------------------------------------------- 1x1 conv via MFMA fp16-split (d0 only)
template <int S, bool RELU, int NOC>
__global__ __launch_bounds__(256) void conv1x1_mfma_k(
    const float* __restrict__ in, const _Float16* __restrict__ wh,
    const float* __restrict__ bias, float* __restrict__ out,
    int IC, int IH, int IW, int OC, int OH, int OW) {
  __shared__ __align__(16) _Float16 ldsH[64 * 40];
  __shared__ __align__(16) _Float16 ldsL[64 * 40];
  int t = threadIdx.x;
  int wv = t >> 6, l = t & 63;
  int px0 = blockIdx.x * 64;
  int ocT0 = blockIdx.y * NOC;
  const int P = OH * OW;
  const int ktiles = IC >> 5;
  const int OCt = OC >> 4;
  int n = l & 15, koff = (l >> 4) * 8;
  f32x4 acc[NOC];
#pragma unroll
  for (int j = 0; j < NOC; ++j) acc[j] = {0.f, 0.f, 0.f, 0.f};
  const half8* wh8 = reinterpret_cast<const half8*>(wh);
  for (int kT = 0; kT < ktiles; ++kT) {
    __syncthreads();
    for (int e = t; e < 2048; e += 256) {
      int pr = e & 63, ic = e >> 6;
      int p = px0 + pr;
      float v;
      if (S == 1) {
        v = in[(size_t)(kT * 32 + ic) * P + p];
      } else {
        int oy = p / OW, ox = p % OW;
        v = in[((size_t)(kT * 32 + ic) * IH + oy * S) * IW + ox * S];
      }
      _Float16 hi = (_Float16)v;
      ldsH[pr * 40 + ic] = hi;
      ldsL[pr * 40 + ic] = (_Float16)(v - (float)hi);
    }
    __syncthreads();
    half8 BH = *reinterpret_cast<const half8*>(&ldsH[(wv * 16 + n) * 40 + koff]);
    half8 BL = *reinterpret_cast<const half8*>(&ldsL[(wv * 16 + n) * 40 + koff]);
#pragma unroll
    for (int j = 0; j < NOC; ++j) {
      half8 AH = wh8[((0 * OCt + (ocT0 + j)) * ktiles + kT) * 64 + l];
      half8 AL = wh8[((1 * OCt + (ocT0 + j)) * ktiles + kT) * 64 + l];
      acc[j] = __builtin_amdgcn_mfma_f32_16x16x32_f16(AH, BH, acc[j], 0, 0, 0);
      acc[j] = __builtin_amdgcn_mfma_f32_16x16x32_f16(AH, BL, acc[j], 0, 0, 0);
      acc[j] = __builtin_amdgcn_mfma_f32_16x16x32_f16(AL, BH, acc[j], 0, 0, 0);
    }
  }
  int p = px0 + wv * 16 + n;
#pragma unroll
  for (int j = 0; j < NOC; ++j) {
    int oc0 = (ocT0 + j) * 16 + ((l >> 4) << 2);
#pragma unroll
    for (int r = 0; r < 4; ++r) {
      int oc = oc0 + r;
      float bv = bias[oc];
      float v32 = __fadd_rn(acc[j][r], bv);
      v32 = __fmul_rn(v32, kBNF);
      if (RELU) v32 = fmaxf(v32, 0.f);
      out[(size_t)oc * P + p] = v32;
    }
  }
}

// ---------------------------------------------------------------- 1x1 conv fp32 (a_sc / b_sc / e; R21-proven)
template <int S, bool RELU>
__global__ __launch_bounds__(256) void conv1x1_k(
    const float* __restrict__ in, const float* __restrict__ w,
    const float* __restrict__ bias, float* __restrict__ out,
    int IC, int IH, int IW, int OC, int OH, int OW) {
  __shared__ float in_s[16][64];
  __shared__ float w_s[16][64];
  const int P = OH * OW;
  int t = threadIdx.x;
  int p0 = blockIdx.x * 64;
  int oc0 = blockIdx.y * 64;
  int oc4 = (t >> 4) * 4, px4 = (t & 15) * 4;
  float acc[4][4] = {};
  for (int ic0 = 0; ic0 < IC; ic0 += 16) {
    __syncthreads();
    {
      int e = t;
#pragma unroll
      for (int k = 0; k < 4; ++k, e += 256) {
        int icr = e >> 6, pxr = e & 63;
        int p = p0 + pxr;
        float v = 0.f;
        if (p < P) {
          int oy = p / OW, ox = p % OW;
          v = in[((ic0 + icr) * IH + oy * S) * IW + ox * S];
        }
        in_s[icr][pxr] = v;
      }
      e = t;
#pragma unroll
      for (int k = 0; k < 4; ++k, e += 256) {
        int icr = e >> 6, ocr = e & 63;
        w_s[icr][ocr] = w[(oc0 + ocr) * IC + ic0 + icr];
      }
    }
    __syncthreads();
#pragma unroll
    for (int icr = 0; icr < 16; ++icr) {
      float4 iv = *reinterpret_cast<const float4*>(&in_s[icr][px4]);
      float4 wv = *reinterpret_cast<const float4*>(&w_s[icr][oc4]);
      const float* ip = (const float*)&iv;
      const float* wp = (const float*)&wv;
#pragma unroll
      for (int o = 0; o < 4; ++o)
#pragma unroll
        for (int p = 0; p < 4; ++p)
          acc[o][p] = fmaf(wp[o], ip[p], acc[o][p]);
    }
  }
  int p = p0 + px4;
  if (p < P) {
    int oy = p / OW, ox = p % OW;
#pragma unroll
    for (int o = 0; o < 4; ++o) {
      int oc = oc0 + oc4 + o;
      float bv = bias[oc];
      float4 rv;
      float* rp = (float*)&rv;
#pragma unroll
      for (int pp = 0; pp < 4; ++pp) {
        float v32 = __fadd_rn(acc[o][pp], bv);
        v32 = __fmul_rn(v32, kBNF);
        if (RELU) v32 = fmaxf(v32, 0.f);
        rp[pp] = v32;
      }
      *reinterpret_cast<float4*>(&out[((size_t)oc * OH + oy) * OW + ox]) = rv;
    }
  }
}

// ---------------------------------------------------------------- 3x3 conv S=1 via MFMA fp16-split, OYT=2 (R25)
template <int NOC>
__global__ __launch_bounds__(256) void conv3s1_mfma_k(
    const float* __restrict__ in, const _Float16* __restrict__ wh,
    const float* __restrict__ bias, const float* __restrict__ skip,
    float* __restrict__ out, int IC, int HW_, int OC) {
  __shared__ __align__(16) _Float16 ldsH[4 * 20 * 40];
  __shared__ __align__(16) _Float16 ldsL[4 * 20 * 40];
  int t = threadIdx.x;
  int wv = t >> 6, l = t & 63;
  int px0 = blockIdx.x * 16;
  int oy0 = blockIdx.y * 2;
  int ocT0 = (blockIdx.z * 4 + wv) * NOC;
  const int ktiles = IC >> 5;
  const int OCt = OC >> 4;
  int n = l & 15, koff = (l >> 4) * 8;
  f32x4 acc[NOC][2];
#pragma unroll
  for (int j = 0; j < NOC; ++j)
#pragma unroll
    for (int r2 = 0; r2 < 2; ++r2) acc[j][r2] = {0.f, 0.f, 0.f, 0.f};
  const half8* wh8 = reinterpret_cast<const half8*>(wh);
  for (int kT = 0; kT < ktiles; ++kT) {
    __syncthreads();
    for (int e = t; e < 2304; e += 256) {
      int xi = e % 18;
      int rem = e / 18;
      int ic = rem & 31, r = rem >> 5;
      int iy = oy0 - 1 + r;
      int ix = px0 - 1 + xi;
      float v = 0.f;
      if (iy >= 0 && iy < HW_ && ix >= 0 && ix < HW_)
        v = in[((size_t)(kT * 32 + ic) * HW_ + iy) * HW_ + ix];
      _Float16 hi = (_Float16)v;
      ldsH[(r * 20 + xi) * 40 + ic] = hi;
      ldsL[(r * 20 + xi) * 40 + ic] = (_Float16)(v - (float)hi);
    }
    __syncthreads();
#pragma unroll
    for (int ky = 0; ky < 3; ++ky) {
#pragma unroll
      for (int kx = 0; kx < 3; ++kx) {
        int tap = ky * 3 + kx;
        half8 BH0 = *reinterpret_cast<const half8*>(&ldsH[((0 + ky) * 20 + n + kx) * 40 + koff]);
        half8 BL0 = *reinterpret_cast<const half8*>(&ldsL[((0 + ky) * 20 + n + kx) * 40 + koff]);
        half8 BH1 = *reinterpret_cast<const half8*>(&ldsH[((1 + ky) * 20 + n + kx) * 40 + koff]);
        half8 BL1 = *reinterpret_cast<const half8*>(&ldsL[((1 + ky) * 20 + n + kx) * 40 + koff]);
#pragma unroll
        for (int j = 0; j < NOC; ++j) {
          half8 AH = wh8[(((tap)*OCt + (ocT0 + j)) * ktiles + kT) * 64 + l];
          half8 AL = wh8[(((9 + tap) * OCt + (ocT0 + j)) * ktiles + kT) * 64 + l];
          acc[j][0] = __builtin_amdgcn_mfma_f32_16x16x32_f16(AH, BH0, acc[j][0], 0, 0, 0);
          acc[j][0] = __builtin_amdgcn_mfma_f32_16x16x32_f16(AH, BL0, acc[j][0], 0, 0, 0);
          acc[j][0] = __builtin_amdgcn_mfma_f32_16x16x32_f16(AL, BH0, acc[j][0], 0, 0, 0);
          acc[j][1] = __builtin_amdgcn_mfma_f32_16x16x32_f16(AH, BH1, acc[j][1], 0, 0, 0);
          acc[j][1] = __builtin_amdgcn_mfma_f32_16x16x32_f16(AH, BL1, acc[j][1], 0, 0, 0);
          acc[j][1] = __builtin_amdgcn_mfma_f32_16x16x32_f16(AL, BH1, acc[j][1], 0, 0, 0);
        }
      }
    }
  }
  int ox = px0 + n;
#pragma unroll
  for (int j = 0; j < NOC; ++j) {
    int oc0 = (ocT0 + j) * 16 + ((l >> 4) << 2);
#pragma unroll
    for (int r2 = 0; r2 < 2; ++r2) {
      int oy = oy0 + r2;
#pragma unroll
      for (int r = 0; r < 4; ++r) {
        int oc = oc0 + r;
        float bv = bias[oc];
        size_t idx = ((size_t)oc * HW_ + oy) * HW_ + ox;
        float v32 = __fadd_rn(acc[j][r2][r], bv);
        v32 = __fmul_rn(v32, kBNF);
        v32 = __fadd_rn(v32, skip[idx]);
        out[idx] = fmaxf(v32, 0.f);
      }
    }
  }
}

// ---------------------------------------------------------------- 3x3 conv S=2 via MFMA fp16-split, parity LDS (R21)
template <int NOC>
__global__ __launch_bounds__(256) void conv3s2_mfma_k(
    const float* __restrict__ in, const _Float16* __restrict__ wh,
    const float* __restrict__ bias, float* __restrict__ out,
    int IC, int IH, int IW, int OC, int OH, int OW) {
  __shared__ __align__(16) _Float16 ldsEH[3 * 17 * 40];
  __shared__ __align__(16) _Float16 ldsEL[3 * 17 * 40];
  __shared__ __align__(16) _Float16 ldsOH[3 * 16 * 40];
  __shared__ __align__(16) _Float16 ldsOL[3 * 16 * 40];
  int t = threadIdx.x;
  int wv = t >> 6, l = t & 63;
  int px0 = blockIdx.x * 16;
  int oy = blockIdx.y;
  int ocT0 = (blockIdx.z * 4 + wv) * NOC;
  const int ktiles = IC >> 5;
  const int OCt = OC >> 4;
  int n = l & 15, koff = (l >> 4) * 8;
  f32x4 acc[NOC];
#pragma unroll
  for (int j = 0; j < NOC; ++j) acc[j] = {0.f, 0.f, 0.f, 0.f};
  const half8* wh8 = reinterpret_cast<const half8*>(wh);
  for (int kT = 0; kT < ktiles; ++kT) {
    __syncthreads();
    for (int e = t; e < 3168; e += 256) {
      int ic = e & 31;
      int rem = e >> 5;
      int xi = rem % 33, ky = rem / 33;
      int iy = oy * 2 - 1 + ky;
      int ix = px0 * 2 - 1 + xi;
      float v = 0.f;
      if (iy >= 0 && iy < IH && ix >= 0 && ix < IW)
        v = in[((size_t)(kT * 32 + ic) * IH + iy) * IW + ix];
      _Float16 hi = (_Float16)v;
      _Float16 lo = (_Float16)(v - (float)hi);
      int hrow = xi >> 1;
      if (xi & 1) {
        ldsOH[(ky * 16 + hrow) * 40 + ic] = hi;
        ldsOL[(ky * 16 + hrow) * 40 + ic] = lo;
      } else {
        ldsEH[(ky * 17 + hrow) * 40 + ic] = hi;
        ldsEL[(ky * 17 + hrow) * 40 + ic] = lo;
      }
    }
    __syncthreads();
#pragma unroll
    for (int ky = 0; ky < 3; ++ky) {
#pragma unroll
      for (int kx = 0; kx < 3; ++kx) {
        int tap = ky * 3 + kx;
        half8 BH, BL;
        if (kx == 0) {
          BH = *reinterpret_cast<const half8*>(&ldsEH[(ky * 17 + n) * 40 + koff]);
          BL = *reinterpret_cast<const half8*>(&ldsEL[(ky * 17 + n) * 40 + koff]);
        } else if (kx == 1) {
          BH = *reinterpret_cast<const half8*>(&ldsOH[(ky * 16 + n) * 40 + koff]);
          BL = *reinterpret_cast<const half8*>(&ldsOL[(ky * 16 + n) * 40 + koff]);
        } else {
          BH = *reinterpret_cast<const half8*>(&ldsEH[(ky * 17 + n + 1) * 40 + koff]);
          BL = *reinterpret_cast<const half8*>(&ldsEL[(ky * 17 + n + 1) * 40 + koff]);
        }
#pragma unroll
        for (int j = 0; j < NOC; ++j) {
          half8 AH = wh8[(((tap)*OCt + (ocT0 + j)) * ktiles + kT) * 64 + l];
          half8 AL = wh8[(((9 + tap) * OCt + (ocT0 + j)) * ktiles + kT) * 64 + l];
          acc[j] = __builtin_amdgcn_mfma_f32_16x16x32_f16(AH, BH, acc[j], 0, 0, 0);
          acc[j] = __builtin_amdgcn_mfma_f32_16x16x32_f16(AH, BL, acc[j], 0, 0, 0);
          acc[j] = __builtin_amdgcn_mfma_f32_16x16x32_f16(AL, BH, acc[j], 0, 0, 0);
        }
      }
    }
  }
  int ox = px0 + n;
#pragma unroll
  for (int j = 0; j < NOC; ++j) {
    int oc0 = (ocT0 + j) * 16 + ((l >> 4) << 2);
#pragma unroll
    for (int r = 0; r < 4; ++r) {
      int oc = oc0 + r;
      float bv = bias[oc];
      size_t idx = ((size_t)oc * OH + oy) * OW + ox;
      float v32 = __fadd_rn(acc[j][r], bv);
      v32 = __fmul_rn(v32, kBNF);
      out[idx] = fmaxf(v32, 0.f);
    }
  }
}

// ---------------------------------------------------------------- ConvT weight prep -> bf16 A-fragments (R14)
__global__ __launch_bounds__(256) void prep_wb_k(const float* __restrict__ w,
                                                 __hip_bfloat16* __restrict__ wb,
                                                 int IC, int OC) {
  int i = blockIdx.x * 256 + threadIdx.x;
  int total = 16 * IC * OC;
  if (i >= total) return;
  int per_cfg = IC * OC;
  int cfg = i / per_cfg;
  int r = i - cfg * per_cfg;
  int ktiles = IC >> 5;
  int ocT = r / (ktiles * 512);
  int r2 = r - ocT * (ktiles * 512);
  int kT = r2 >> 9;
  int f = r2 & 511;
  int lane = f >> 3, e = f & 7;
  int m = lane & 15, kk = ((lane >> 4) << 3) + e;
  int oc = ocT * 16 + m, ic = kT * 32 + kk;
  int kyb = cfg >> 3, ty = (cfg >> 2) & 1, kx = cfg & 3;
  int ky = kyb + 2 * ty;
  wb[i] = __float2bfloat16(w[((size_t)ic * OC + oc) * 16 + ky * 4 + kx]);
}

// ---------------------------------------------------------------- ConvT k4 s2 p1 via MFMA bf16 (R14, validated)
__global__ __launch_bounds__(256) void convt_mfma_k(
    const float* __restrict__ in, const __hip_bfloat16* __restrict__ wb,
    const float* __restrict__ bias, float* __restrict__ out,
    int IC, int IH, int IW, int OC, int OH, int OW) {
  __shared__ __align__(16) __hip_bfloat16 lds[2 * 18 * 40];
  int t = threadIdx.x;
  int wv = t >> 6, l = t & 63;
  int ox0 = blockIdx.x * 32;
  int oy = blockIdx.y;
  int oc0w = blockIdx.z * 64 + wv * 16;
  int kyb = (oy & 1) ? 0 : 1;
  int hb = ox0 >> 1;
  int iy0n = oy + 1 - kyb;
  int iy0 = iy0n >> 1;
  bool ok0 = (iy0 < IH);
  int iy1n = oy + 1 - kyb - 2;
  int iy1 = iy1n >> 1;
  bool ok1 = (iy1n >= 0) && (iy1 < IH);
  f32x4 accE = {0.f, 0.f, 0.f, 0.f};
  f32x4 accO = {0.f, 0.f, 0.f, 0.f};
  const int ktiles = IC >> 5;
  int n = l & 15, koff = (l >> 4) * 8;
  const short8* wb8 = reinterpret_cast<const short8*>(wb);
  int ocT = oc0w >> 4;
  const int OCt = OC >> 4;
  for (int kT = 0; kT < ktiles; ++kT) {
    __syncthreads();
    for (int e = t; e < 1152; e += 256) {
      int ic = e / 36;
      int r = e - ic * 36;
      int ty = r / 18, xi = r - ty * 18;
      int ix = hb - 1 + xi;
      int iy = ty ? iy1 : iy0;
      bool ok = ty ? ok1 : ok0;
      float v = 0.f;
      if (ok && ix >= 0 && ix < IW)
        v = in[((size_t)(kT * 32 + ic) * IH + iy) * IW + ix];
      lds[(ty * 18 + xi) * 40 + ic] = __float2bfloat16(v);
    }
    __syncthreads();
#pragma unroll
    for (int ty = 0; ty < 2; ++ty) {
      short8 A0 = wb8[((((kyb * 2 + ty) * 4 + 0) * OCt + ocT) * ktiles + kT) * 64 + l];
      short8 A1 = wb8[((((kyb * 2 + ty) * 4 + 1) * OCt + ocT) * ktiles + kT) * 64 + l];
      short8 A2 = wb8[((((kyb * 2 + ty) * 4 + 2) * OCt + ocT) * ktiles + kT) * 64 + l];
      short8 A3 = wb8[((((kyb * 2 + ty) * 4 + 3) * OCt + ocT) * ktiles + kT) * 64 + l];
      short8 b0 = *reinterpret_cast<const short8*>(&lds[(ty * 18 + 0 + n) * 40 + koff]);
      short8 b1 = *reinterpret_cast<const short8*>(&lds[(ty * 18 + 1 + n) * 40 + koff]);
      short8 b2 = *reinterpret_cast<const short8*>(&lds[(ty * 18 + 2 + n) * 40 + koff]);
      accE = __builtin_amdgcn_mfma_f32_16x16x32_bf16(A1, b1, accE, 0, 0, 0);
      accE = __builtin_amdgcn_mfma_f32_16x16x32_bf16(A3, b0, accE, 0, 0, 0);
      accO = __builtin_amdgcn_mfma_f32_16x16x32_bf16(A0, b2, accO, 0, 0, 0);
      accO = __builtin_amdgcn_mfma_f32_16x16x32_bf16(A2, b1, accO, 0, 0, 0);
    }
  }
  int ocr0 = oc0w + ((l >> 4) << 2);
  int oxE = ox0 + 2 * n;
  int oxO = ox0 + 1 + 2 * n;
#pragma unroll
  for (int r = 0; r < 4; ++r) {
    float bv = bias[ocr0 + r];
    size_t rowbase = ((size_t)(ocr0 + r) * OH + oy) * OW;
    out[rowbase + oxE] = fmaxf((accE[r] + bv) * kBNF, 0.f);
    out[rowbase + oxO] = fmaxf((accO[r] + bv) * kBNF, 0.f);
  }
}

// ---------------------------------------------------------------- final 3x3 conv 128->1 + sigmoid, half-rows (R10)
__global__ __launch_bounds__(192) void dow_k(const float* __restrict__ in,
                                             const float* __restrict__ w,
                                             const float* __restrict__ bias,
                                             float* __restrict__ out) {
  const int H = 320, W = 320, IC = 128;
  int oy = blockIdx.y;
  int ox0 = blockIdx.x * 160;
  int tx = threadIdx.x;
  __shared__ float in_s[4][3][164];
  __shared__ float w_s[IC * 9];
  for (int e = tx; e < IC * 9; e += 192) w_s[e] = w[e];
  float acc = 0.f;
  for (int ic0 = 0; ic0 < IC; ic0 += 4) {
    __syncthreads();
    for (int e = tx; e < 4 * 3 * 162; e += 192) {
      int icr = e / 486;
      int rem = e - icr * 486;
      int r = rem / 162, c = rem - r * 162;
      int iy = oy + r - 1, ix = ox0 + c - 1;
      float v = 0.f;
      if (iy >= 0 && iy < H && ix >= 0 && ix < W)
        v = in[((ic0 + icr) * H + iy) * W + ix];
      in_s[icr][r][c] = v;
    }
    __syncthreads();
    if (tx < 160) {
#pragma unroll
      for (int icr = 0; icr < 4; ++icr)
#pragma unroll
        for (int r = 0; r < 3; ++r)
#pragma unroll
          for (int c = 0; c < 3; ++c)
            acc = fmaf(w_s[(ic0 + icr) * 9 + r * 3 + c], in_s[icr][r][tx + c], acc);
    }
  }
  if (tx < 160) {
    acc += bias[0];
    out[oy * W + ox0 + tx] = 1.f / (1.f + expf(-acc));
  }
}

// ---------------------------------------------------------------- codebook sq-norms: numpy-pairwise fp32
__global__ __launch_bounds__(256) void cbprep_np(const float* __restrict__ cb,
                                                 float* __restrict__ c2f) {
  int e = blockIdx.x, t = threadIdx.x;
  __shared__ float a[256];
  a[t] = cb[e * 256 + t];
  __syncthreads();
  if (t == 0) {
    float tot = 0.f;
    for (int h = 0; h < 2; ++h) {
      const float* p = a + h * 128;
      float r[8];
#pragma unroll
      for (int j = 0; j < 8; ++j) r[j] = __fmul_rn(p[j], p[j]);
      for (int i = 8; i < 128; i += 8)
#pragma unroll
        for (int j = 0; j < 8; ++j) r[j] = __fadd_rn(r[j], __fmul_rn(p[i + j], p[i + j]));
      float s = __fadd_rn(__fadd_rn(__fadd_rn(r[0], r[1]), __fadd_rn(r[2], r[3])),
                          __fadd_rn(__fadd_rn(r[4], r[5]), __fadd_rn(r[6], r[7])));
      tot = (h == 0) ? s : __fadd_rn(tot, s);
    }
    c2f[e] = tot;
  }
}

// ---------------------------------------------------------------- VQ: 4 rows/block, 512 threads (2 entries/thread)
__global__ __launch_bounds__(512) void vq_ref_k(const float* __restrict__ z,
                                                const float* __restrict__ cb,
                                                const float* __restrict__ c2f,
                                                float* __restrict__ zq_out,
                                                float* __restrict__ idx_out) {
  int n0 = blockIdx.x * 4;
  int t = threadIdx.x;
  __shared__ float f[4][256];
  __shared__ float dist[4][1024];
  __shared__ float rr[4][2][8];
  __shared__ float f2s[4];
  __shared__ int bestIdx[4];
  for (int e = t; e < 1024; e += 512) {
    int r = e >> 8, c = e & 255;
    f[r][c] = z[(size_t)(n0 + r) * 256 + c];
  }
  __syncthreads();
  if (t < 64) {
    int row = t >> 4, hh = (t >> 3) & 1, j = t & 7;
    const float* p = f[row] + hh * 128;
    float r = __fmul_rn(p[j], p[j]);
    for (int i = 8; i < 128; i += 8) r = __fadd_rn(r, __fmul_rn(p[i + j], p[i + j]));
    rr[row][hh][j] = r;
  }
  __syncthreads();
  if (t < 4) {
    float s0 = __fadd_rn(__fadd_rn(__fadd_rn(rr[t][0][0], rr[t][0][1]), __fadd_rn(rr[t][0][2], rr[t][0][3])),
                         __fadd_rn(__fadd_rn(rr[t][0][4], rr[t][0][5]), __fadd_rn(rr[t][0][6], rr[t][0][7])));
    float s1 = __fadd_rn(__fadd_rn(__fadd_rn(rr[t][1][0], rr[t][1][1]), __fadd_rn(rr[t][1][2], rr[t][1][3])),
                         __fadd_rn(__fadd_rn(rr[t][1][4], rr[t][1][5]), __fadd_rn(rr[t][1][6], rr[t][1][7])));
    f2s[t] = __fadd_rn(s0, s1);
  }
  __syncthreads();
  for (int e = t; e < 1024; e += 512) {
    const float4* cbe = reinterpret_cast<const float4*>(cb + (size_t)e * 256);
    double d0 = 0.0, d1 = 0.0, d2 = 0.0, d3 = 0.0;
    for (int d = 0; d < 64; ++d) {
      float4 c4 = cbe[d];
      float4 f0 = *reinterpret_cast<const float4*>(&f[0][d * 4]);
      float4 f1 = *reinterpret_cast<const float4*>(&f[1][d * 4]);
      float4 f2v = *reinterpret_cast<const float4*>(&f[2][d * 4]);
      float4 f3 = *reinterpret_cast<const float4*>(&f[3][d * 4]);
      d0 = fma((double)f0.x, (double)c4.x, d0); d0 = fma((double)f0.y, (double)c4.y, d0);
      d0 = fma((double)f0.z, (double)c4.z, d0); d0 = fma((double)f0.w, (double)c4.w, d0);
      d1 = fma((double)f1.x, (double)c4.x, d1); d1 = fma((double)f1.y, (double)c4.y, d1);
      d1 = fma((double)f1.z, (double)c4.z, d1); d1 = fma((double)f1.w, (double)c4.w, d1);
      d2 = fma((double)f2v.x, (double)c4.x, d2); d2 = fma((double)f2v.y, (double)c4.y, d2);
      d2 = fma((double)f2v.z, (double)c4.z, d2); d2 = fma((double)f2v.w, (double)c4.w, d2);
      d3 = fma((double)f3.x, (double)c4.x, d3); d3 = fma((double)f3.y, (double)c4.y, d3);
      d3 = fma((double)f3.z, (double)c4.z, d3); d3 = fma((double)f3.w, (double)c4.w, d3);
    }
    float c2e = c2f[e];
    dist[0][e] = __fsub_rn(__fadd_rn(f2s[0], c2e), __fmul_rn(2.f, (float)d0));
    dist[1][e] = __fsub_rn(__fadd_rn(f2s[1], c2e), __fmul_rn(2.f, (float)d1));
    dist[2][e] = __fsub_rn(__fadd_rn(f2s[2], c2e), __fmul_rn(2.f, (float)d2));
    dist[3][e] = __fsub_rn(__fadd_rn(f2s[3], c2e), __fmul_rn(2.f, (float)d3));
  }
  __syncthreads();
  if (t < 256) {
    int row = t >> 6, l = t & 63;
    float bv = dist[row][l];
    int bi = l;
    for (int e = l + 64; e < 1024; e += 64) {
      float v = dist[row][e];
      if (v < bv) { bv = v; bi = e; }
    }
#pragma unroll
    for (int m = 1; m < 64; m <<= 1) {
      float ov = __shfl_xor(bv, m, 64);
      int oi = __shfl_xor(bi, m, 64);
      if (ov < bv || (ov == bv && oi < bi)) { bv = ov; bi = oi; }
    }
    if (l == 0) {
      bestIdx[row] = bi;
      idx_out[n0 + row] = (float)bi;
    }
  }
  __syncthreads();
  if (t < 256) {
#pragma unroll
    for (int r = 0; r < 4; ++r)
      zq_out[(size_t)(n0 + r) * 256 + t] = cb[(size_t)bestIdx[r] * 256 + t];
  }
}

// ================================================================ host
extern "C" void kernel_launch(void* const* d_in, const int* in_sizes, int n_in,
                              void* d_out, int out_size, void* d_ws, size_t ws_size,
                              hipStream_t stream) {
  const float* x = (const float*)d_in[0];
  const float* w0 = (const float*)d_in[1];
  const float* b0 = (const float*)d_in[2];
  const float* a_c1w = (const float*)d_in[3];
  const float* a_c1b = (const float*)d_in[4];
  const float* a_c2w = (const float*)d_in[5];
  const float* a_c2b = (const float*)d_in[6];
  const float* a_scw = (const float*)d_in[7];
  const float* a_scb = (const float*)d_in[8];
  const float* b_c1w = (const float*)d_in[9];
  const float* b_c1b = (const float*)d_in[10];
  const float* b_c2w = (const float*)d_in[11];
  const float* b_c2b = (const float*)d_in[12];
  const float* b_scw = (const float*)d_in[13];
  const float* b_scb = (const float*)d_in[14];
  const float* ew = (const float*)d_in[15];
  const float* eb = (const float*)d_in[16];
  const float* cb = (const float*)d_in[17];
  const float* d0w = (const float*)d_in[18];
  const float* d0b = (const float*)d_in[19];
  const float* dt1w = (const float*)d_in[20];
  const float* dt1b = (const float*)d_in[21];
  const float* dt2w = (const float*)d_in[22];
  const float* dt2b = (const float*)d_in[23];
  const float* doww = (const float*)d_in[24];
  const float* dob = (const float*)d_in[25];

  // ws (floats): A 13.1M | B 6.55M | C 6.55M | c2f 1k (layout = R21-proven)
  float* ws = (float*)d_ws;
  float* A = ws;
  float* Bf = ws + 13107200;
  float* Cf = ws + 19660800;
  float* c2f = ws + 26214400;
  _Float16* wh_ac1 = (_Float16*)(void*)Cf;
  _Float16* wh_bc1 = (_Float16*)(void*)(Bf + 3300000);
  _Float16* wh_ac2 = (_Float16*)(void*)(A + 6600000);
  _Float16* wh_bc2 = (_Float16*)(void*)(A + 3300000);
  _Float16* wh_d0  = (_Float16*)(void*)(A + 10000000);
  __hip_bfloat16* wb_dt1 = (__hip_bfloat16*)(void*)A;
  __hip_bfloat16* wb_dt2 = (__hip_bfloat16*)(void*)(Bf + 3400000);

  float* outf = (float*)d_out;
  float* recon = outf;
  float* zq = outf + 409600;
  float* idxo = zq + 6553600;

  cbprep_np<<<1024, 256, 0, stream>>>(cb, c2f);

  for (int b = 0; b < 4; ++b) {
    const float* xb = x + (size_t)b * 102400;
    float* zqb = zq + (size_t)b * 1638400;
    float* idxb = idxo + (size_t)b * 6400;
    float* reconb = recon + (size_t)b * 102400;

    // encoder (z chain bit-identical)
    conv0_k<<<dim3(320, 2), 320, 0, stream>>>(xb, w0, b0, A);          // A = h0
    prep_w3h_k<<<2304, 256, 0, stream>>>(a_c1w, wh_ac1, 128, 256);
    conv3s2_mfma_k<2><<<dim3(10, 160, 2), 256, 0, stream>>>(
        A, wh_ac1, a_c1b, Bf, 128, 320, 320, 256, 160, 160);           // Bf = a_c1
    conv1x1_k<2, false><<<dim3(400, 4), 256, 0, stream>>>(
        A, a_scw, a_scb, Cf, 128, 320, 320, 256, 160, 160);            // Cf = a_sc (fp32)
    prep_w3h_k<<<4608, 256, 0, stream>>>(a_c2w, wh_ac2, 256, 256);
    conv3s1_mfma_k<2><<<dim3(10, 80, 2), 256, 0, stream>>>(
        Bf, wh_ac2, a_c2b, Cf, A, 256, 160, 256);                      // A = a_out (OYT=2)
    prep_w3h_k<<<9216, 256, 0, stream>>>(b_c1w, wh_bc1, 256, 512);
    conv3s2_mfma_k<2><<<dim3(5, 80, 4), 256, 0, stream>>>(
        A, wh_bc1, b_c1b, Bf, 256, 160, 160, 512, 80, 80);             // Bf = b_c1
    conv1x1_k<2, false><<<dim3(100, 8), 256, 0, stream>>>(
        A, b_scw, b_scb, Cf, 256, 160, 160, 512, 80, 80);              // Cf = b_sc (fp32)
    prep_w3h_k<<<18432, 256, 0, stream>>>(b_c2w, wh_bc2, 512, 512);
    conv3s1_mfma_k<2><<<dim3(5, 40, 4), 256, 0, stream>>>(
        Bf, wh_bc2, b_c2b, Cf, A, 512, 80, 512);                       // A = b_out (OYT=2)
    conv1x1_k<1, false><<<dim3(100, 4), 256, 0, stream>>>(
        A, ew, eb, Cf, 512, 80, 80, 256, 80, 80);                      // Cf = z (fp32)
    // VQ (512 threads, per-entry arithmetic identical)
    vq_ref_k<<<1600, 512, 0, stream>>>(Cf, cb, c2f, zqb, idxb);
    // decoder
    prep_w1h_k<<<1024, 256, 0, stream>>>(d0w, wh_d0, 256, 512);
    conv1x1_mfma_k<1, true, 2><<<dim3(100, 16), 256, 0, stream>>>(
        zqb, wh_d0, d0b, Bf, 256, 80, 80, 512, 80, 80);                // Bf = g0
    prep_wb_k<<<8192, 256, 0, stream>>>(dt1w, wb_dt1, 512, 256);
    convt_mfma_k<<<dim3(5, 160, 4), 256, 0, stream>>>(
        Bf, wb_dt1, dt1b, Cf, 512, 80, 80, 256, 160, 160);             // Cf = g1
    prep_wb_k<<<2048, 256, 0, stream>>>(dt2w, wb_dt2, 256, 128);
    convt_mfma_k<<<dim3(10, 320, 2), 256, 0, stream>>>(
        Cf, wb_dt2, dt2b, A, 256, 160, 160, 128, 320, 320);            // A = g2
    dow_k<<<dim3(2, 320), 192, 0, stream>>>(A, doww, dob, reconb);
  }
}